// Round 10
// baseline (205.401 us; speedup 1.0000x reference)
//
#include <hip/hip_runtime.h>
#include <hip/hip_fp16.h>

// Geo_GCN, zero-global-atomic pipeline + W pulled through the edge sum:
//   out[n] = b + dinv[n] * sum_e w_e * y[c_e],   y = x @ W^T  (fp16)
// Build: hist2 -> scan -> scatcol -> coldinv -> scatter1 (split payload) ->
//        sort2 -> ygemm (4 nodes/wave, 8 FMA chains) -> gather (register
//        accum, 8 edges in flight/wave, no LDS, direct store).

constexpr int NN   = 100000;
constexpr int NE   = 1600000;
constexpr int D    = 64;
constexpr int NBUK = (NN + 63) / 64;          // 1563 buckets of 64 nodes
constexpr int HB   = 256;                     // chunk-parallel grid
constexpr int HT   = 1024;
constexpr int CHUNK = NE / HB;                // 6250 (exact)
constexpr int NSC  = NBUK * HB;               // 400128 per hist
constexpr int NSC2 = 2 * NSC;                 // row + col hists, one scan
constexpr int SCB  = 1024;
constexpr int SCG  = (NSC2 + SCB - 1) / SCB;  // 782

// ---- pass 1: both bucket histograms in LDS; no global atomics ----
__global__ void __launch_bounds__(HT)
hist2_kernel(const int* __restrict__ row, const int* __restrict__ col,
             int* __restrict__ hist) {
    __shared__ int hr[NBUK], hc[NBUK];
    const int t = threadIdx.x;
    for (int i = t; i < NBUK; i += HT) { hr[i] = 0; hc[i] = 0; }
    __syncthreads();
    const int e0 = blockIdx.x * CHUNK;
    for (int e = e0 + t; e < e0 + CHUNK; e += HT) {
        atomicAdd(&hr[row[e] >> 6], 1);
        atomicAdd(&hc[col[e] >> 6], 1);
    }
    __syncthreads();
    for (int i = t; i < NBUK; i += HT) {
        hist[i * HB + blockIdx.x]       = hr[i];
        hist[NSC + i * HB + blockIdx.x] = hc[i];
    }
}

// ---- combined exclusive scan over hist[NSC2] ----
__global__ void scanpart_kernel(const int* __restrict__ a, int* __restrict__ bsum) {
    __shared__ int red[16];
    const int t = threadIdx.x;
    const int i = blockIdx.x * SCB + t;
    int s = (i < NSC2) ? a[i] : 0;
    #pragma unroll
    for (int o = 1; o < 64; o <<= 1) s += __shfl_xor(s, o);
    if ((t & 63) == 0) red[t >> 6] = s;
    __syncthreads();
    if (t < 16) {
        int ss = red[t];
        #pragma unroll
        for (int o = 1; o < 16; o <<= 1) ss += __shfl_xor(ss, o);
        if (t == 0) bsum[blockIdx.x] = ss;
    }
}

__global__ void scanblk_kernel(const int* __restrict__ bsum, int* __restrict__ boff) {
    __shared__ int wsum[16], wsum2[16];
    const int t = threadIdx.x;              // 1024
    const int lane = t & 63;
    const int w = t >> 6;
    const int v = (t < SCG) ? bsum[t] : 0;
    int s = v;
    #pragma unroll
    for (int o = 1; o < 64; o <<= 1) { int u = __shfl_up(s, o); if (lane >= o) s += u; }
    if (lane == 63) wsum[w] = s;
    __syncthreads();
    if (t < 16) {
        int ss = wsum[t];
        #pragma unroll
        for (int o = 1; o < 16; o <<= 1) { int u = __shfl_up(ss, o); if (t >= o) ss += u; }
        wsum2[t] = ss;
    }
    __syncthreads();
    const int excl = (w ? wsum2[w - 1] : 0) + (s - v);
    if (t < SCG) boff[t] = excl;
}

// in-place: hist -> exclusive offsets (each thread touches only its own element)
__global__ void scanfinal_kernel(int* __restrict__ a, const int* __restrict__ boff) {
    __shared__ int wsum[16], wsum2[16];
    const int t = threadIdx.x;
    const int i = blockIdx.x * SCB + t;
    const int lane = t & 63;
    const int w = t >> 6;
    const int v = (i < NSC2) ? a[i] : 0;
    int s = v;
    #pragma unroll
    for (int o = 1; o < 64; o <<= 1) { int u = __shfl_up(s, o); if (lane >= o) s += u; }
    if (lane == 63) wsum[w] = s;
    __syncthreads();
    if (t < 16) {
        int ss = wsum[t];
        #pragma unroll
        for (int o = 1; o < 16; o <<= 1) { int u = __shfl_up(ss, o); if (t >= o) ss += u; }
        wsum2[t] = ss;
    }
    __syncthreads();
    const int excl = boff[blockIdx.x] + (w ? wsum2[w - 1] : 0) + (s - v);
    if (i < NSC2) a[i] = excl;
}

// ---- col digits into col-buckets (LDS cursors) ----
__global__ void __launch_bounds__(HT)
scatcol_kernel(const int* __restrict__ col, const int* __restrict__ hoff,
               unsigned char* __restrict__ colidx) {
    __shared__ int cur[NBUK];
    const int t = threadIdx.x;
    for (int i = t; i < NBUK; i += HT) cur[i] = hoff[NSC + i * HB + blockIdx.x] - NE;
    __syncthreads();
    const int e0 = blockIdx.x * CHUNK;
    for (int e = e0 + t; e < e0 + CHUNK; e += HT) {
        const int c = col[e];
        const int pos = atomicAdd(&cur[c >> 6], 1);
        colidx[pos] = (unsigned char)(c & 63);
    }
}

// ---- per-bucket exact degree count -> dinv ----
__global__ void __launch_bounds__(256)
coldinv_kernel(const int* __restrict__ hoff, const unsigned char* __restrict__ colidx,
               float* __restrict__ dinv) {
    __shared__ int cnt[64];
    const int t = threadIdx.x;
    const int b = blockIdx.x;
    if (t < 64) cnt[t] = 0;
    __syncthreads();
    const int s0 = hoff[NSC + b * HB] - NE;
    const int s1 = (b + 1 < NBUK) ? (hoff[NSC + (b + 1) * HB] - NE) : NE;
    for (int k = s0 + t; k < s1; k += 256) atomicAdd(&cnt[colidx[k]], 1);
    __syncthreads();
    if (t < 64) {
        const int n = b * 64 + t;
        if (n < NN) {
            const int d = cnt[t];
            dinv[n] = (d > 0) ? rsqrtf((float)d) : 0.0f;
        }
    }
}

// ---- edges into row-buckets, split payload: epay = (w15<<17)|c, er6 = r&63 ----
__global__ void __launch_bounds__(HT)
scatter1_kernel(const int* __restrict__ row, const int* __restrict__ col,
                const float* __restrict__ dist, const float* __restrict__ dinv,
                const int* __restrict__ hoff, unsigned* __restrict__ epay,
                unsigned char* __restrict__ er6) {
    __shared__ int cur[NBUK];
    const int t = threadIdx.x;
    for (int i = t; i < NBUK; i += HT) cur[i] = hoff[i * HB + blockIdx.x];
    __syncthreads();
    const int e0 = blockIdx.x * CHUNK;
    for (int e = e0 + t; e < e0 + CHUNK; e += HT) {
        const int r = row[e];
        const int c = col[e];
        const float dv = dist[e];
        const float wv = expf(-dv * dv) * dinv[c];               // (0, 1]
        const unsigned w15 = (unsigned)(wv * 32767.0f + 0.5f);
        const int pos = atomicAdd(&cur[r >> 6], 1);              // LDS atomic
        epay[pos] = (w15 << 17) | (unsigned)c;
        er6[pos]  = (unsigned char)(r & 63);
    }
}

// ---- per-bucket counting sort by r&63 -> node-grouped 4B edges + rowstart ----
__global__ void __launch_bounds__(256)
sort2_kernel(const int* __restrict__ hoff, const unsigned* __restrict__ epay,
             const unsigned char* __restrict__ er6,
             unsigned* __restrict__ edges4, int* __restrict__ rowstart) {
    __shared__ int cnt[64], cur[64];
    const int t = threadIdx.x;
    const int b = blockIdx.x;
    if (t < 64) cnt[t] = 0;
    __syncthreads();
    const int s0 = hoff[b * HB];
    const int s1 = (b + 1 < NBUK) ? hoff[(b + 1) * HB] : NE;
    for (int k = s0 + t; k < s1; k += 256) atomicAdd(&cnt[er6[k]], 1);
    __syncthreads();
    if (t < 64) {
        const int v = cnt[t];
        int s = v;
        #pragma unroll
        for (int o = 1; o < 64; o <<= 1) { int u = __shfl_up(s, o); if (t >= o) s += u; }
        const int excl = s - v;
        cur[t] = excl;
        rowstart[b * 64 + t] = s0 + excl;      // start of node b*64+t
        if (b == NBUK - 1 && t == 63) rowstart[NBUK * 64] = NE;
    }
    __syncthreads();
    for (int k = s0 + t; k < s1; k += 256) {
        const int pos = s0 + atomicAdd(&cur[er6[k]], 1);
        edges4[pos] = epay[k];
    }
}

// ---- y = x @ W^T (fp16). W row j=lane in 64 VGPRs; 4 nodes per wave
// iteration x 2 accumulators per node = 8 independent FMA chains. ----
__global__ void __launch_bounds__(256)
ygemm_kernel(const float* __restrict__ x, const float* __restrict__ W,
             __half* __restrict__ y) {
    const int lane = threadIdx.x & 63;
    float wr[64];
    #pragma unroll
    for (int k4 = 0; k4 < 16; ++k4) {
        const float4 w4 = *reinterpret_cast<const float4*>(W + (size_t)lane * 64 + k4 * 4);
        wr[k4 * 4 + 0] = w4.x; wr[k4 * 4 + 1] = w4.y;
        wr[k4 * 4 + 2] = w4.z; wr[k4 * 4 + 3] = w4.w;
    }
    const int wid = (blockIdx.x * 256 + threadIdx.x) >> 6;
    const int nw  = (gridDim.x * 256) >> 6;
    for (int n0 = wid * 4; n0 < NN; n0 += nw * 4) {
        float accA[4] = {0.f, 0.f, 0.f, 0.f};
        float accB[4] = {0.f, 0.f, 0.f, 0.f};
        #pragma unroll
        for (int k4 = 0; k4 < 16; ++k4) {
            #pragma unroll
            for (int j = 0; j < 4; ++j) {
                const int n = (n0 + j < NN) ? (n0 + j) : (NN - 1);
                const float4 xv = *reinterpret_cast<const float4*>(x + (size_t)n * 64 + k4 * 4);
                accA[j] += xv.x * wr[k4 * 4 + 0] + xv.y * wr[k4 * 4 + 1];
                accB[j] += xv.z * wr[k4 * 4 + 2] + xv.w * wr[k4 * 4 + 3];
            }
        }
        #pragma unroll
        for (int j = 0; j < 4; ++j) {
            const int n = n0 + j;
            if (n < NN) y[(size_t)n * 64 + lane] = __float2half(accA[j] + accB[j]);
        }
    }
}

// ---- per-node register gather over y (8 edges in flight/wave), direct store ----
__global__ void __launch_bounds__(256)
gather_kernel(const int* __restrict__ rowstart, const unsigned* __restrict__ edges4,
              const float* __restrict__ dinvg, const __half* __restrict__ y,
              const float* __restrict__ bias, float* __restrict__ out) {
    const int t = threadIdx.x;
    const int lane = t & 63;
    const int wv = t >> 6;
    const int sub = lane >> 3;        // which of 8 concurrent edges
    const int ch8 = (lane & 7) << 3;  // 8 channels per lane
    constexpr float WSCL = 1.0f / 32767.0f;
    const float4 b0 = *reinterpret_cast<const float4*>(bias + ch8);
    const float4 b1 = *reinterpret_cast<const float4*>(bias + ch8 + 4);

    const int nwaves = gridDim.x * 4;
    for (int n = blockIdx.x * 4 + wv; n < NN; n += nwaves) {
        const int s0 = rowstart[n];
        const int s1 = rowstart[n + 1];
        float a0 = 0.f, a1 = 0.f, a2 = 0.f, a3 = 0.f;
        float a4 = 0.f, a5 = 0.f, a6 = 0.f, a7 = 0.f;
        for (int p0 = s0; p0 < s1; p0 += 8) {
            const int pp = p0 + sub;
            const int ppc = (pp < s1) ? pp : (s1 - 1);    // clamped -> valid load
            const unsigned m = edges4[ppc];
            const int c = (int)(m & 0x1FFFFu);
            float wgt = (float)(m >> 17) * WSCL;
            wgt = (pp < s1) ? wgt : 0.0f;
            const float4 raw = *reinterpret_cast<const float4*>(y + (size_t)c * 64 + ch8);
            const __half2* h2 = reinterpret_cast<const __half2*>(&raw);
            const float2 f0 = __half22float2(h2[0]);
            const float2 f1 = __half22float2(h2[1]);
            const float2 f2 = __half22float2(h2[2]);
            const float2 f3 = __half22float2(h2[3]);
            a0 += wgt * f0.x; a1 += wgt * f0.y; a2 += wgt * f1.x; a3 += wgt * f1.y;
            a4 += wgt * f2.x; a5 += wgt * f2.y; a6 += wgt * f3.x; a7 += wgt * f3.y;
        }
        #pragma unroll
        for (int o = 8; o < 64; o <<= 1) {
            a0 += __shfl_xor(a0, o); a1 += __shfl_xor(a1, o);
            a2 += __shfl_xor(a2, o); a3 += __shfl_xor(a3, o);
            a4 += __shfl_xor(a4, o); a5 += __shfl_xor(a5, o);
            a6 += __shfl_xor(a6, o); a7 += __shfl_xor(a7, o);
        }
        if (sub == 0) {
            const float dn = dinvg[n];
            const float4 o0 = make_float4(b0.x + dn * a0, b0.y + dn * a1,
                                          b0.z + dn * a2, b0.w + dn * a3);
            const float4 o1 = make_float4(b1.x + dn * a4, b1.y + dn * a5,
                                          b1.z + dn * a6, b1.w + dn * a7);
            float* op = out + (size_t)n * 64 + ch8;
            *reinterpret_cast<float4*>(op)     = o0;
            *reinterpret_cast<float4*>(op + 4) = o1;
        }
    }
}

extern "C" void kernel_launch(void* const* d_in, const int* in_sizes, int n_in,
                              void* d_out, int out_size, void* d_ws, size_t ws_size,
                              hipStream_t stream) {
    const float* x    = (const float*)d_in[0];
    const int*   ei   = (const int*)d_in[1];
    const float* dist = (const float*)d_in[2];
    const float* W    = (const float*)d_in[3];
    const float* b    = (const float*)d_in[4];
    float* out = (float*)d_out;

    const int* row = ei;
    const int* col = ei + NE;

    // workspace (~20 MB):
    //   [edges4 u32*NE | YREG (y fp16 NN*64  ALIASES  build-only arrays) |
    //    rowstart | dinv]
    // build-only arrays (all dead before ygemm): epay, er6, hist, colidx,
    // bsum, boff.
    unsigned* edges4 = (unsigned*)d_ws;                     // NE u32 (6.4 MB)
    char*     ybase  = (char*)(edges4 + NE);
    __half*   y      = (__half*)ybase;                      // NN*64 half (12.8 MB)
    unsigned* epay   = (unsigned*)ybase;                    // NE u32 (6.4 MB)
    unsigned char* er6 = (unsigned char*)(epay + NE);       // NE u8 (1.6 MB)
    int*      hist   = (int*)(er6 + NE);                    // NSC2 (3.2 MB) -> hoff in place
    unsigned char* colidx = (unsigned char*)(hist + NSC2);  // NE u8 (1.6 MB)
    int*      bsum   = (int*)(colidx + NE);                 // SCG
    int*      boff   = bsum + SCG;                          // SCG
    // end of build alias region ~12.81 MB; y needs 12.80 MB
    constexpr size_t YREG = ((size_t)NE * 4 + NE + (size_t)NSC2 * 4 + NE
                             + 2 * (size_t)SCG * 4 + 15) & ~(size_t)15;
    int*   rowstart = (int*)(ybase + YREG);                 // NBUK*64+1
    float* dinv     = (float*)(rowstart + NBUK * 64 + 1);   // NN

    hist2_kernel    <<<HB, HT, 0, stream>>>(row, col, hist);
    scanpart_kernel <<<SCG, SCB, 0, stream>>>(hist, bsum);
    scanblk_kernel  <<<1, 1024, 0, stream>>>(bsum, boff);
    scanfinal_kernel<<<SCG, SCB, 0, stream>>>(hist, boff);
    scatcol_kernel  <<<HB, HT, 0, stream>>>(col, hist, colidx);
    coldinv_kernel  <<<NBUK, 256, 0, stream>>>(hist, colidx, dinv);
    scatter1_kernel <<<HB, HT, 0, stream>>>(row, col, dist, dinv, hist, epay, er6);
    sort2_kernel    <<<NBUK, 256, 0, stream>>>(hist, epay, er6, edges4, rowstart);
    ygemm_kernel    <<<2048, 256, 0, stream>>>(x, W, y);
    gather_kernel   <<<4096, 256, 0, stream>>>(rowstart, edges4, dinv, y, b, out);
}

// Round 11
// 131.636 us; speedup vs baseline: 1.5604x; 1.5604x over previous
//
#include <hip/hip_runtime.h>
#include <hip/hip_fp16.h>

// Geo_GCN, zero-global-atomic pipeline + W pulled through the edge sum:
//   out[n] = b + dinv[n] * sum_e w_e * y[c_e],   y = x @ W^T  (fp16, MFMA)
// Build: hist2 -> scan -> scatcol -> coldinv -> scatter1 -> sort2 (round-9
// int2 payload). ygemm: MFMA 16x16x32_f16, W held as 8 register fragments.
// gather: register accum, 8 edges in flight/wave, no LDS, direct store.

constexpr int NN   = 100000;
constexpr int NE   = 1600000;
constexpr int D    = 64;
constexpr int NBUK = (NN + 63) / 64;          // 1563 buckets of 64 nodes
constexpr int HB   = 256;                     // chunk-parallel grid
constexpr int HT   = 1024;
constexpr int CHUNK = NE / HB;                // 6250 (exact)
constexpr int NSC  = NBUK * HB;               // 400128 per hist
constexpr int NSC2 = 2 * NSC;                 // row + col hists, one scan
constexpr int SCB  = 1024;
constexpr int SCG  = (NSC2 + SCB - 1) / SCB;  // 782

using f16x8 = __attribute__((ext_vector_type(8))) _Float16;
using f32x4 = __attribute__((ext_vector_type(4))) float;

// ---- pass 1: both bucket histograms in LDS; no global atomics ----
__global__ void __launch_bounds__(HT)
hist2_kernel(const int* __restrict__ row, const int* __restrict__ col,
             int* __restrict__ hist) {
    __shared__ int hr[NBUK], hc[NBUK];
    const int t = threadIdx.x;
    for (int i = t; i < NBUK; i += HT) { hr[i] = 0; hc[i] = 0; }
    __syncthreads();
    const int e0 = blockIdx.x * CHUNK;
    for (int e = e0 + t; e < e0 + CHUNK; e += HT) {
        atomicAdd(&hr[row[e] >> 6], 1);
        atomicAdd(&hc[col[e] >> 6], 1);
    }
    __syncthreads();
    for (int i = t; i < NBUK; i += HT) {
        hist[i * HB + blockIdx.x]       = hr[i];
        hist[NSC + i * HB + blockIdx.x] = hc[i];
    }
}

// ---- combined exclusive scan over hist[NSC2] ----
__global__ void scanpart_kernel(const int* __restrict__ a, int* __restrict__ bsum) {
    __shared__ int red[16];
    const int t = threadIdx.x;
    const int i = blockIdx.x * SCB + t;
    int s = (i < NSC2) ? a[i] : 0;
    #pragma unroll
    for (int o = 1; o < 64; o <<= 1) s += __shfl_xor(s, o);
    if ((t & 63) == 0) red[t >> 6] = s;
    __syncthreads();
    if (t < 16) {
        int ss = red[t];
        #pragma unroll
        for (int o = 1; o < 16; o <<= 1) ss += __shfl_xor(ss, o);
        if (t == 0) bsum[blockIdx.x] = ss;
    }
}

__global__ void scanblk_kernel(const int* __restrict__ bsum, int* __restrict__ boff) {
    __shared__ int wsum[16], wsum2[16];
    const int t = threadIdx.x;              // 1024
    const int lane = t & 63;
    const int w = t >> 6;
    const int v = (t < SCG) ? bsum[t] : 0;
    int s = v;
    #pragma unroll
    for (int o = 1; o < 64; o <<= 1) { int u = __shfl_up(s, o); if (lane >= o) s += u; }
    if (lane == 63) wsum[w] = s;
    __syncthreads();
    if (t < 16) {
        int ss = wsum[t];
        #pragma unroll
        for (int o = 1; o < 16; o <<= 1) { int u = __shfl_up(ss, o); if (t >= o) ss += u; }
        wsum2[t] = ss;
    }
    __syncthreads();
    const int excl = (w ? wsum2[w - 1] : 0) + (s - v);
    if (t < SCG) boff[t] = excl;
}

// in-place: hist -> exclusive offsets (each thread touches only its own element)
__global__ void scanfinal_kernel(int* __restrict__ a, const int* __restrict__ boff) {
    __shared__ int wsum[16], wsum2[16];
    const int t = threadIdx.x;
    const int i = blockIdx.x * SCB + t;
    const int lane = t & 63;
    const int w = t >> 6;
    const int v = (i < NSC2) ? a[i] : 0;
    int s = v;
    #pragma unroll
    for (int o = 1; o < 64; o <<= 1) { int u = __shfl_up(s, o); if (lane >= o) s += u; }
    if (lane == 63) wsum[w] = s;
    __syncthreads();
    if (t < 16) {
        int ss = wsum[t];
        #pragma unroll
        for (int o = 1; o < 16; o <<= 1) { int u = __shfl_up(ss, o); if (t >= o) ss += u; }
        wsum2[t] = ss;
    }
    __syncthreads();
    const int excl = boff[blockIdx.x] + (w ? wsum2[w - 1] : 0) + (s - v);
    if (i < NSC2) a[i] = excl;
}

// ---- col digits into col-buckets (LDS cursors) ----
__global__ void __launch_bounds__(HT)
scatcol_kernel(const int* __restrict__ col, const int* __restrict__ hoff,
               unsigned char* __restrict__ colidx) {
    __shared__ int cur[NBUK];
    const int t = threadIdx.x;
    for (int i = t; i < NBUK; i += HT) cur[i] = hoff[NSC + i * HB + blockIdx.x] - NE;
    __syncthreads();
    const int e0 = blockIdx.x * CHUNK;
    for (int e = e0 + t; e < e0 + CHUNK; e += HT) {
        const int c = col[e];
        const int pos = atomicAdd(&cur[c >> 6], 1);
        colidx[pos] = (unsigned char)(c & 63);
    }
}

// ---- per-bucket exact degree count -> dinv ----
__global__ void __launch_bounds__(256)
coldinv_kernel(const int* __restrict__ hoff, const unsigned char* __restrict__ colidx,
               float* __restrict__ dinv) {
    __shared__ int cnt[64];
    const int t = threadIdx.x;
    const int b = blockIdx.x;
    if (t < 64) cnt[t] = 0;
    __syncthreads();
    const int s0 = hoff[NSC + b * HB] - NE;
    const int s1 = (b + 1 < NBUK) ? (hoff[NSC + (b + 1) * HB] - NE) : NE;
    for (int k = s0 + t; k < s1; k += 256) atomicAdd(&cnt[colidx[k]], 1);
    __syncthreads();
    if (t < 64) {
        const int n = b * 64 + t;
        if (n < NN) {
            const int d = cnt[t];
            dinv[n] = (d > 0) ? rsqrtf((float)d) : 0.0f;
        }
    }
}

// ---- edges into row-buckets; weight = 15-bit fp of exp(-d^2)*dinv[c] ----
__global__ void __launch_bounds__(HT)
scatter1_kernel(const int* __restrict__ row, const int* __restrict__ col,
                const float* __restrict__ dist, const float* __restrict__ dinv,
                const int* __restrict__ hoff, int2* __restrict__ edges8) {
    __shared__ int cur[NBUK];
    const int t = threadIdx.x;
    for (int i = t; i < NBUK; i += HT) cur[i] = hoff[i * HB + blockIdx.x];
    __syncthreads();
    const int e0 = blockIdx.x * CHUNK;
    for (int e = e0 + t; e < e0 + CHUNK; e += HT) {
        const int r = row[e];
        const int c = col[e];
        const float dv = dist[e];
        const float wv = expf(-dv * dv) * dinv[c];               // (0, 1]
        const unsigned w15 = (unsigned)(wv * 32767.0f + 0.5f);
        const int pos = atomicAdd(&cur[r >> 6], 1);              // LDS atomic
        edges8[pos] = make_int2((int)((w15 << 17) | (unsigned)c), r);
    }
}

// ---- per-bucket counting sort by r&63 -> node-grouped 4B edges + rowstart ----
__global__ void __launch_bounds__(256)
sort2_kernel(const int* __restrict__ hoff, const int2* __restrict__ edges8,
             unsigned* __restrict__ edges4, int* __restrict__ rowstart) {
    __shared__ int cnt[64], cur[64];
    const int t = threadIdx.x;
    const int b = blockIdx.x;
    if (t < 64) cnt[t] = 0;
    __syncthreads();
    const int s0 = hoff[b * HB];
    const int s1 = (b + 1 < NBUK) ? hoff[(b + 1) * HB] : NE;
    for (int k = s0 + t; k < s1; k += 256) atomicAdd(&cnt[edges8[k].y & 63], 1);
    __syncthreads();
    if (t < 64) {
        const int v = cnt[t];
        int s = v;
        #pragma unroll
        for (int o = 1; o < 64; o <<= 1) { int u = __shfl_up(s, o); if (t >= o) s += u; }
        const int excl = s - v;
        cur[t] = excl;
        rowstart[b * 64 + t] = s0 + excl;      // start of node b*64+t
        if (b == NBUK - 1 && t == 63) rowstart[NBUK * 64] = NE;
    }
    __syncthreads();
    for (int k = s0 + t; k < s1; k += 256) {
        const int2 m = edges8[k];
        const int pos = s0 + atomicAdd(&cur[m.y & 63], 1);
        edges4[pos] = (unsigned)m.x;
    }
}

// ---- y = x @ W^T via MFMA f16 (fp32 accumulate), y stored fp16. ----
// Per wave: W held as 8 f16x8 B-fragments (32 VGPRs, loaded once).
// Node tile = 16 rows; A-fragment: lane holds x[n0+(lane&15)][8*(lane>>4)+i]
// (+32 for the 2nd K-half). C/D: col=lane&15, row=(lane>>4)*4+reg (m89 layout).
__global__ void __launch_bounds__(256)
ygemm_kernel(const float* __restrict__ x, const float* __restrict__ W,
             __half* __restrict__ y) {
    const int t = threadIdx.x;
    const int m  = t & 15;      // A row / B col / C col within tile
    const int kb = (t & 63) >> 4;  // k-block 0..3
    f16x8 bf[4][2];             // [ch-tile][k-half]
    #pragma unroll
    for (int jt = 0; jt < 4; ++jt) {
        #pragma unroll
        for (int kh = 0; kh < 2; ++kh) {
            const float* wp = W + (size_t)(jt * 16 + m) * 64 + kh * 32 + kb * 8;
            const float4 w0 = *reinterpret_cast<const float4*>(wp);
            const float4 w1 = *reinterpret_cast<const float4*>(wp + 4);
            f16x8 f;
            f[0] = (_Float16)w0.x; f[1] = (_Float16)w0.y;
            f[2] = (_Float16)w0.z; f[3] = (_Float16)w0.w;
            f[4] = (_Float16)w1.x; f[5] = (_Float16)w1.y;
            f[6] = (_Float16)w1.z; f[7] = (_Float16)w1.w;
            bf[jt][kh] = f;
        }
    }
    const int wid = (blockIdx.x * 256 + t) >> 6;
    const int nw  = (gridDim.x * 256) >> 6;
    for (int nt = wid; nt < NN / 16; nt += nw) {   // NN/16 = 6250 exact
        const int n0 = nt * 16;
        f16x8 af[2];
        #pragma unroll
        for (int kh = 0; kh < 2; ++kh) {
            const float* xp = x + (size_t)(n0 + m) * 64 + kh * 32 + kb * 8;
            const float4 x0 = *reinterpret_cast<const float4*>(xp);
            const float4 x1 = *reinterpret_cast<const float4*>(xp + 4);
            f16x8 f;
            f[0] = (_Float16)x0.x; f[1] = (_Float16)x0.y;
            f[2] = (_Float16)x0.z; f[3] = (_Float16)x0.w;
            f[4] = (_Float16)x1.x; f[5] = (_Float16)x1.y;
            f[6] = (_Float16)x1.z; f[7] = (_Float16)x1.w;
            af[kh] = f;
        }
        #pragma unroll
        for (int jt = 0; jt < 4; ++jt) {
            f32x4 acc = {0.f, 0.f, 0.f, 0.f};
            acc = __builtin_amdgcn_mfma_f32_16x16x32_f16(af[0], bf[jt][0], acc, 0, 0, 0);
            acc = __builtin_amdgcn_mfma_f32_16x16x32_f16(af[1], bf[jt][1], acc, 0, 0, 0);
            #pragma unroll
            for (int r = 0; r < 4; ++r) {
                y[(size_t)(n0 + kb * 4 + r) * 64 + jt * 16 + m] = __float2half(acc[r]);
            }
        }
    }
}

// ---- per-node register gather over y (8 edges in flight/wave), direct store ----
__global__ void __launch_bounds__(256)
gather_kernel(const int* __restrict__ rowstart, const unsigned* __restrict__ edges4,
              const float* __restrict__ dinvg, const __half* __restrict__ y,
              const float* __restrict__ bias, float* __restrict__ out) {
    const int t = threadIdx.x;
    const int lane = t & 63;
    const int wv = t >> 6;
    const int sub = lane >> 3;        // which of 8 concurrent edges
    const int ch8 = (lane & 7) << 3;  // 8 channels per lane
    constexpr float WSCL = 1.0f / 32767.0f;
    const float4 b0 = *reinterpret_cast<const float4*>(bias + ch8);
    const float4 b1 = *reinterpret_cast<const float4*>(bias + ch8 + 4);

    const int nwaves = gridDim.x * 4;
    for (int n = blockIdx.x * 4 + wv; n < NN; n += nwaves) {
        const int s0 = rowstart[n];
        const int s1 = rowstart[n + 1];
        float a0 = 0.f, a1 = 0.f, a2 = 0.f, a3 = 0.f;
        float a4 = 0.f, a5 = 0.f, a6 = 0.f, a7 = 0.f;
        for (int p0 = s0; p0 < s1; p0 += 8) {
            const int pp = p0 + sub;
            const int ppc = (pp < s1) ? pp : (s1 - 1);    // clamped -> valid load
            const unsigned m = edges4[ppc];
            const int c = (int)(m & 0x1FFFFu);
            float wgt = (float)(m >> 17) * WSCL;
            wgt = (pp < s1) ? wgt : 0.0f;
            const float4 raw = *reinterpret_cast<const float4*>(y + (size_t)c * 64 + ch8);
            const __half2* h2 = reinterpret_cast<const __half2*>(&raw);
            const float2 f0 = __half22float2(h2[0]);
            const float2 f1 = __half22float2(h2[1]);
            const float2 f2 = __half22float2(h2[2]);
            const float2 f3 = __half22float2(h2[3]);
            a0 += wgt * f0.x; a1 += wgt * f0.y; a2 += wgt * f1.x; a3 += wgt * f1.y;
            a4 += wgt * f2.x; a5 += wgt * f2.y; a6 += wgt * f3.x; a7 += wgt * f3.y;
        }
        #pragma unroll
        for (int o = 8; o < 64; o <<= 1) {
            a0 += __shfl_xor(a0, o); a1 += __shfl_xor(a1, o);
            a2 += __shfl_xor(a2, o); a3 += __shfl_xor(a3, o);
            a4 += __shfl_xor(a4, o); a5 += __shfl_xor(a5, o);
            a6 += __shfl_xor(a6, o); a7 += __shfl_xor(a7, o);
        }
        if (sub == 0) {
            const float dn = dinvg[n];
            const float4 o0 = make_float4(b0.x + dn * a0, b0.y + dn * a1,
                                          b0.z + dn * a2, b0.w + dn * a3);
            const float4 o1 = make_float4(b1.x + dn * a4, b1.y + dn * a5,
                                          b1.z + dn * a6, b1.w + dn * a7);
            float* op = out + (size_t)n * 64 + ch8;
            *reinterpret_cast<float4*>(op)     = o0;
            *reinterpret_cast<float4*>(op + 4) = o1;
        }
    }
}

extern "C" void kernel_launch(void* const* d_in, const int* in_sizes, int n_in,
                              void* d_out, int out_size, void* d_ws, size_t ws_size,
                              hipStream_t stream) {
    const float* x    = (const float*)d_in[0];
    const int*   ei   = (const int*)d_in[1];
    const float* dist = (const float*)d_in[2];
    const float* W    = (const float*)d_in[3];
    const float* b    = (const float*)d_in[4];
    float* out = (float*)d_out;

    const int* row = ei;
    const int* col = ei + NE;

    // workspace (~24.9 MB). y (12.8 MB) ALIASES edges8: edges8 is dead after
    // sort2; ygemm runs after sort2 on the same stream.
    int2*     edges8   = (int2*)d_ws;                       // NE int2 (12.8 MB)
    __half*   y        = (__half*)d_ws;                     // NN*64 half (12.8 MB)
    unsigned* edges4   = (unsigned*)(edges8 + NE);          // NE u32 (6.4 MB)
    int*      hist     = (int*)(edges4 + NE);               // NSC2 (3.2 MB) -> hoff in place
    int*      rowstart = hist + NSC2;                       // NBUK*64+1 (~400 KB)
    float*    dinv     = (float*)(rowstart + NBUK * 64 + 1);// NN
    int*      bsum     = (int*)(dinv + NN);                 // SCG
    int*      boff     = bsum + SCG;                        // SCG
    unsigned char* colidx = (unsigned char*)(boff + SCG);   // NE bytes (1.6 MB)

    hist2_kernel    <<<HB, HT, 0, stream>>>(row, col, hist);
    scanpart_kernel <<<SCG, SCB, 0, stream>>>(hist, bsum);
    scanblk_kernel  <<<1, 1024, 0, stream>>>(bsum, boff);
    scanfinal_kernel<<<SCG, SCB, 0, stream>>>(hist, boff);
    scatcol_kernel  <<<HB, HT, 0, stream>>>(col, hist, colidx);
    coldinv_kernel  <<<NBUK, 256, 0, stream>>>(hist, colidx, dinv);
    scatter1_kernel <<<HB, HT, 0, stream>>>(row, col, dist, dinv, hist, edges8);
    sort2_kernel    <<<NBUK, 256, 0, stream>>>(hist, edges8, edges4, rowstart);
    ygemm_kernel    <<<1024, 256, 0, stream>>>(x, W, y);
    gather_kernel   <<<4096, 256, 0, stream>>>(rowstart, edges4, dinv, y, b, out);
}

// Round 12
// 125.415 us; speedup vs baseline: 1.6378x; 1.0496x over previous
//
#include <hip/hip_runtime.h>
#include <hip/hip_fp16.h>

// Geo_GCN, zero-global-atomic pipeline + W pulled through the edge sum:
//   out[n] = b + dinv[n] * sum_e w_e * y[c_e],   y = x @ W^T  (fp16, MFMA)
// Build: hist2 (row>>7, col>>8 LDS hists) -> combined scan -> scatcol ->
//        coldinv -> scatter1 (dinv folded into 15-bit weight, 64B runs) ->
//        sort2 (LDS-staged single-read counting sort -> node-grouped edges4)
// Then:  ygemm (MFMA 16x16x32_f16, W as register fragments, y fp16 aliasing
//        edges8) -> gather (register accum, 8 edges in flight/wave, no LDS).

constexpr int NN   = 100000;
constexpr int NE   = 1600000;
constexpr int D    = 64;
constexpr int NRB  = (NN + 127) / 128;        // 782 row-buckets of 128 nodes
constexpr int NCB  = (NN + 255) / 256;        // 391 col-buckets of 256 nodes
constexpr int HB   = 256;                     // chunk-parallel grid
constexpr int HT   = 1024;
constexpr int CHUNK = NE / HB;                // 6250 (exact)
constexpr int NSR  = NRB * HB;                // 200192 row-hist elements
constexpr int NSCC = NCB * HB;                // 100096 col-hist elements
constexpr int NST  = NSR + NSCC;              // 300288 combined scan
constexpr int SCB  = 1024;
constexpr int SCG  = (NST + SCB - 1) / SCB;   // 294 scan blocks
constexpr int CAP  = 3072;                    // sort2 LDS stage cap (mean 2046)

using f16x8 = __attribute__((ext_vector_type(8))) _Float16;
using f32x4 = __attribute__((ext_vector_type(4))) float;

// ---- pass 1: both bucket histograms in LDS; no global atomics ----
__global__ void __launch_bounds__(HT)
hist2_kernel(const int* __restrict__ row, const int* __restrict__ col,
             int* __restrict__ hist) {
    __shared__ int hr[NRB], hc[NCB];
    const int t = threadIdx.x;
    for (int i = t; i < NRB; i += HT) hr[i] = 0;
    for (int i = t; i < NCB; i += HT) hc[i] = 0;
    __syncthreads();
    const int e0 = blockIdx.x * CHUNK;
    for (int e = e0 + t; e < e0 + CHUNK; e += HT) {
        atomicAdd(&hr[row[e] >> 7], 1);
        atomicAdd(&hc[col[e] >> 8], 1);
    }
    __syncthreads();
    for (int i = t; i < NRB; i += HT) hist[i * HB + blockIdx.x] = hr[i];
    for (int i = t; i < NCB; i += HT) hist[NSR + i * HB + blockIdx.x] = hc[i];
}

// ---- combined exclusive scan over hist[NST] ----
__global__ void scanpart_kernel(const int* __restrict__ a, int* __restrict__ bsum) {
    __shared__ int red[16];
    const int t = threadIdx.x;
    const int i = blockIdx.x * SCB + t;
    int s = (i < NST) ? a[i] : 0;
    #pragma unroll
    for (int o = 1; o < 64; o <<= 1) s += __shfl_xor(s, o);
    if ((t & 63) == 0) red[t >> 6] = s;
    __syncthreads();
    if (t < 16) {
        int ss = red[t];
        #pragma unroll
        for (int o = 1; o < 16; o <<= 1) ss += __shfl_xor(ss, o);
        if (t == 0) bsum[blockIdx.x] = ss;
    }
}

__global__ void scanblk_kernel(const int* __restrict__ bsum, int* __restrict__ boff) {
    __shared__ int wsum[8], wsum2[8];
    const int t = threadIdx.x;          // 512
    const int lane = t & 63;
    const int w = t >> 6;               // 0..7
    const int v = (t < SCG) ? bsum[t] : 0;
    int s = v;
    #pragma unroll
    for (int o = 1; o < 64; o <<= 1) { int u = __shfl_up(s, o); if (lane >= o) s += u; }
    if (lane == 63) wsum[w] = s;
    __syncthreads();
    if (t < 8) {
        int ss = wsum[t];
        #pragma unroll
        for (int o = 1; o < 8; o <<= 1) { int u = __shfl_up(ss, o); if (t >= o) ss += u; }
        wsum2[t] = ss;
    }
    __syncthreads();
    const int excl = (w ? wsum2[w - 1] : 0) + (s - v);
    if (t < SCG) boff[t] = excl;
}

// in-place: hist -> exclusive offsets
__global__ void scanfinal_kernel(int* __restrict__ a, const int* __restrict__ boff) {
    __shared__ int wsum[16], wsum2[16];
    const int t = threadIdx.x;
    const int i = blockIdx.x * SCB + t;
    const int lane = t & 63;
    const int w = t >> 6;
    const int v = (i < NST) ? a[i] : 0;
    int s = v;
    #pragma unroll
    for (int o = 1; o < 64; o <<= 1) { int u = __shfl_up(s, o); if (lane >= o) s += u; }
    if (lane == 63) wsum[w] = s;
    __syncthreads();
    if (t < 16) {
        int ss = wsum[t];
        #pragma unroll
        for (int o = 1; o < 16; o <<= 1) { int u = __shfl_up(ss, o); if (t >= o) ss += u; }
        wsum2[t] = ss;
    }
    __syncthreads();
    const int excl = boff[blockIdx.x] + (w ? wsum2[w - 1] : 0) + (s - v);
    if (i < NST) a[i] = excl;
}

// ---- col digits into col-buckets (LDS cursors); digit = c & 255 ----
__global__ void __launch_bounds__(HT)
scatcol_kernel(const int* __restrict__ col, const int* __restrict__ hoff,
               unsigned char* __restrict__ colidx) {
    __shared__ int cur[NCB];
    const int t = threadIdx.x;
    for (int i = t; i < NCB; i += HT) cur[i] = hoff[NSR + i * HB + blockIdx.x] - NE;
    __syncthreads();
    const int e0 = blockIdx.x * CHUNK;
    for (int e = e0 + t; e < e0 + CHUNK; e += HT) {
        const int c = col[e];
        const int pos = atomicAdd(&cur[c >> 8], 1);
        colidx[pos] = (unsigned char)(c & 255);
    }
}

// ---- per-col-bucket exact degree count -> dinv (256 nodes/bucket) ----
__global__ void __launch_bounds__(256)
coldinv_kernel(const int* __restrict__ hoff, const unsigned char* __restrict__ colidx,
               float* __restrict__ dinv) {
    __shared__ int cnt[256];
    const int t = threadIdx.x;
    const int b = blockIdx.x;
    cnt[t] = 0;
    __syncthreads();
    const int s0 = hoff[NSR + b * HB] - NE;
    const int s1 = (b + 1 < NCB) ? (hoff[NSR + (b + 1) * HB] - NE) : NE;
    for (int k = s0 + t; k < s1; k += 256) atomicAdd(&cnt[colidx[k]], 1);
    __syncthreads();
    const int n = b * 256 + t;
    if (n < NN) {
        const int d = cnt[t];
        dinv[n] = (d > 0) ? rsqrtf((float)d) : 0.0f;
    }
}

// ---- edges into row-buckets; weight = 15-bit fp of exp(-d^2)*dinv[c] ----
__global__ void __launch_bounds__(HT)
scatter1_kernel(const int* __restrict__ row, const int* __restrict__ col,
                const float* __restrict__ dist, const float* __restrict__ dinv,
                const int* __restrict__ hoff, int2* __restrict__ edges8) {
    __shared__ int cur[NRB];
    const int t = threadIdx.x;
    for (int i = t; i < NRB; i += HT) cur[i] = hoff[i * HB + blockIdx.x];
    __syncthreads();
    const int e0 = blockIdx.x * CHUNK;
    for (int e = e0 + t; e < e0 + CHUNK; e += HT) {
        const int r = row[e];
        const int c = col[e];
        const float dv = dist[e];
        const float wv = expf(-dv * dv) * dinv[c];               // (0, 1]
        const unsigned w15 = (unsigned)(wv * 32767.0f + 0.5f);
        const int pos = atomicAdd(&cur[r >> 7], 1);              // LDS atomic
        edges8[pos] = make_int2((int)((w15 << 17) | (unsigned)c), r);
    }
}

// ---- per-bucket LDS-staged counting sort by r&127 -> edges4 + rowstart ----
__global__ void __launch_bounds__(256)
sort2_kernel(const int* __restrict__ hoff, const int2* __restrict__ edges8,
             unsigned* __restrict__ edges4, int* __restrict__ rowstart) {
    __shared__ int2 raw8[CAP];       // 24KB staged bucket edges
    __shared__ int cnt[128], cur[128], wtot[2];
    const int t = threadIdx.x;
    const int b = blockIdx.x;
    const int lane = t & 63;
    if (t < 128) cnt[t] = 0;
    const int s0 = hoff[b * HB];
    const int s1 = (b + 1 < NRB) ? hoff[(b + 1) * HB] : NE;
    int ne = s1 - s0;
    ne = (ne < CAP) ? ne : CAP;      // impossible overflow guard (mean 2046)
    for (int k = t; k < ne; k += 256) raw8[k] = edges8[s0 + k];
    __syncthreads();
    for (int k = t; k < ne; k += 256) atomicAdd(&cnt[raw8[k].y & 127], 1);
    __syncthreads();
    int s = 0, v = 0;
    if (t < 128) {
        v = cnt[t];
        s = v;
        #pragma unroll
        for (int o = 1; o < 64; o <<= 1) { int u = __shfl_up(s, o); if (lane >= o) s += u; }
        if (lane == 63) wtot[t >> 6] = s;
    }
    __syncthreads();
    if (t < 128) {
        const int excl = (s - v) + ((t >= 64) ? wtot[0] : 0);
        cur[t] = excl;
        rowstart[b * 128 + t] = s0 + excl;   // covers rowstart[NN] (last bucket)
    }
    __syncthreads();
    for (int k = t; k < ne; k += 256) {
        const int pos = atomicAdd(&cur[raw8[k].y & 127], 1);
        edges4[s0 + pos] = (unsigned)raw8[k].x;
    }
}

// ---- y = x @ W^T via MFMA f16 (fp32 accumulate), y stored fp16. ----
// Per wave: W held as 8 f16x8 B-fragments (32 VGPRs, loaded once).
// A-fragment: lane holds x[n0+(lane&15)][8*(lane>>4)+i] (+32 for 2nd K-half).
// C/D: col=lane&15, row=(lane>>4)*4+reg (m89-verified layout).
__global__ void __launch_bounds__(256)
ygemm_kernel(const float* __restrict__ x, const float* __restrict__ W,
             __half* __restrict__ y) {
    const int t = threadIdx.x;
    const int m  = t & 15;
    const int kb = (t & 63) >> 4;
    f16x8 bf[4][2];
    #pragma unroll
    for (int jt = 0; jt < 4; ++jt) {
        #pragma unroll
        for (int kh = 0; kh < 2; ++kh) {
            const float* wp = W + (size_t)(jt * 16 + m) * 64 + kh * 32 + kb * 8;
            const float4 w0 = *reinterpret_cast<const float4*>(wp);
            const float4 w1 = *reinterpret_cast<const float4*>(wp + 4);
            f16x8 f;
            f[0] = (_Float16)w0.x; f[1] = (_Float16)w0.y;
            f[2] = (_Float16)w0.z; f[3] = (_Float16)w0.w;
            f[4] = (_Float16)w1.x; f[5] = (_Float16)w1.y;
            f[6] = (_Float16)w1.z; f[7] = (_Float16)w1.w;
            bf[jt][kh] = f;
        }
    }
    const int wid = (blockIdx.x * 256 + t) >> 6;
    const int nw  = (gridDim.x * 256) >> 6;
    for (int nt = wid; nt < NN / 16; nt += nw) {   // 6250 tiles exact
        const int n0 = nt * 16;
        f16x8 af[2];
        #pragma unroll
        for (int kh = 0; kh < 2; ++kh) {
            const float* xp = x + (size_t)(n0 + m) * 64 + kh * 32 + kb * 8;
            const float4 x0 = *reinterpret_cast<const float4*>(xp);
            const float4 x1 = *reinterpret_cast<const float4*>(xp + 4);
            f16x8 f;
            f[0] = (_Float16)x0.x; f[1] = (_Float16)x0.y;
            f[2] = (_Float16)x0.z; f[3] = (_Float16)x0.w;
            f[4] = (_Float16)x1.x; f[5] = (_Float16)x1.y;
            f[6] = (_Float16)x1.z; f[7] = (_Float16)x1.w;
            af[kh] = f;
        }
        #pragma unroll
        for (int jt = 0; jt < 4; ++jt) {
            f32x4 acc = {0.f, 0.f, 0.f, 0.f};
            acc = __builtin_amdgcn_mfma_f32_16x16x32_f16(af[0], bf[jt][0], acc, 0, 0, 0);
            acc = __builtin_amdgcn_mfma_f32_16x16x32_f16(af[1], bf[jt][1], acc, 0, 0, 0);
            #pragma unroll
            for (int r = 0; r < 4; ++r) {
                y[(size_t)(n0 + kb * 4 + r) * 64 + jt * 16 + m] = __float2half(acc[r]);
            }
        }
    }
}

// ---- per-node register gather over y (8 edges in flight/wave), direct store ----
__global__ void __launch_bounds__(256)
gather_kernel(const int* __restrict__ rowstart, const unsigned* __restrict__ edges4,
              const float* __restrict__ dinvg, const __half* __restrict__ y,
              const float* __restrict__ bias, float* __restrict__ out) {
    const int t = threadIdx.x;
    const int lane = t & 63;
    const int wv = t >> 6;
    const int sub = lane >> 3;        // which of 8 concurrent edges
    const int ch8 = (lane & 7) << 3;  // 8 channels per lane
    constexpr float WSCL = 1.0f / 32767.0f;
    const float4 b0 = *reinterpret_cast<const float4*>(bias + ch8);
    const float4 b1 = *reinterpret_cast<const float4*>(bias + ch8 + 4);

    const int nwaves = gridDim.x * 4;
    for (int n = blockIdx.x * 4 + wv; n < NN; n += nwaves) {
        const int s0 = rowstart[n];
        const int s1 = rowstart[n + 1];
        float a0 = 0.f, a1 = 0.f, a2 = 0.f, a3 = 0.f;
        float a4 = 0.f, a5 = 0.f, a6 = 0.f, a7 = 0.f;
        for (int p0 = s0; p0 < s1; p0 += 8) {
            const int pp = p0 + sub;
            const int ppc = (pp < s1) ? pp : (s1 - 1);    // clamped -> valid load
            const unsigned m = edges4[ppc];
            const int c = (int)(m & 0x1FFFFu);
            float wgt = (float)(m >> 17) * WSCL;
            wgt = (pp < s1) ? wgt : 0.0f;
            const float4 raw = *reinterpret_cast<const float4*>(y + (size_t)c * 64 + ch8);
            const __half2* h2 = reinterpret_cast<const __half2*>(&raw);
            const float2 f0 = __half22float2(h2[0]);
            const float2 f1 = __half22float2(h2[1]);
            const float2 f2 = __half22float2(h2[2]);
            const float2 f3 = __half22float2(h2[3]);
            a0 += wgt * f0.x; a1 += wgt * f0.y; a2 += wgt * f1.x; a3 += wgt * f1.y;
            a4 += wgt * f2.x; a5 += wgt * f2.y; a6 += wgt * f3.x; a7 += wgt * f3.y;
        }
        #pragma unroll
        for (int o = 8; o < 64; o <<= 1) {
            a0 += __shfl_xor(a0, o); a1 += __shfl_xor(a1, o);
            a2 += __shfl_xor(a2, o); a3 += __shfl_xor(a3, o);
            a4 += __shfl_xor(a4, o); a5 += __shfl_xor(a5, o);
            a6 += __shfl_xor(a6, o); a7 += __shfl_xor(a7, o);
        }
        if (sub == 0) {
            const float dn = dinvg[n];
            const float4 o0 = make_float4(b0.x + dn * a0, b0.y + dn * a1,
                                          b0.z + dn * a2, b0.w + dn * a3);
            const float4 o1 = make_float4(b1.x + dn * a4, b1.y + dn * a5,
                                          b1.z + dn * a6, b1.w + dn * a7);
            float* op = out + (size_t)n * 64 + ch8;
            *reinterpret_cast<float4*>(op)     = o0;
            *reinterpret_cast<float4*>(op + 4) = o1;
        }
    }
}

extern "C" void kernel_launch(void* const* d_in, const int* in_sizes, int n_in,
                              void* d_out, int out_size, void* d_ws, size_t ws_size,
                              hipStream_t stream) {
    const float* x    = (const float*)d_in[0];
    const int*   ei   = (const int*)d_in[1];
    const float* dist = (const float*)d_in[2];
    const float* W    = (const float*)d_in[3];
    const float* b    = (const float*)d_in[4];
    float* out = (float*)d_out;

    const int* row = ei;
    const int* col = ei + NE;

    // workspace (~22.8 MB). y (12.8 MB) ALIASES edges8: edges8 is dead after
    // sort2; ygemm runs after sort2 on the same stream.
    int2*     edges8   = (int2*)d_ws;                       // NE int2 (12.8 MB)
    __half*   y        = (__half*)d_ws;                     // NN*64 half (12.8 MB)
    unsigned* edges4   = (unsigned*)(edges8 + NE);          // NE u32 (6.4 MB)
    int*      hist     = (int*)(edges4 + NE);               // NST (1.2 MB) -> hoff in place
    int*      rowstart = hist + NST;                        // NRB*128+1 (~400 KB)
    float*    dinv     = (float*)(rowstart + NRB * 128 + 1);// NN
    int*      bsum     = (int*)(dinv + NN);                 // SCG
    int*      boff     = bsum + SCG;                        // SCG
    unsigned char* colidx = (unsigned char*)(boff + SCG);   // NE bytes (1.6 MB)

    hist2_kernel    <<<HB, HT, 0, stream>>>(row, col, hist);
    scanpart_kernel <<<SCG, SCB, 0, stream>>>(hist, bsum);
    scanblk_kernel  <<<1, 512, 0, stream>>>(bsum, boff);
    scanfinal_kernel<<<SCG, SCB, 0, stream>>>(hist, boff);
    scatcol_kernel  <<<HB, HT, 0, stream>>>(col, hist, colidx);
    coldinv_kernel  <<<NCB, 256, 0, stream>>>(hist, colidx, dinv);
    scatter1_kernel <<<HB, HT, 0, stream>>>(row, col, dist, dinv, hist, edges8);
    sort2_kernel    <<<NRB, 256, 0, stream>>>(hist, edges8, edges4, rowstart);
    ygemm_kernel    <<<1024, 256, 0, stream>>>(x, W, y);
    gather_kernel   <<<4096, 256, 0, stream>>>(rowstart, edges4, dinv, y, b, out);
}

// Round 13
// 120.543 us; speedup vs baseline: 1.7040x; 1.0404x over previous
//
#include <hip/hip_runtime.h>
#include <hip/hip_fp16.h>

// Geo_GCN, zero-global-atomic pipeline + W pulled through the edge sum:
//   out[n] = b + dinv[n] * sum_e w_e * dinv[c_e] * y[c_e],  y = x @ W^T (fp16, MFMA)
// Edge record = ONE u32: digit(r&127)<<25 | w8<<17 | c(17b).
// Pipeline: ygemm -> hist2 -> scan x3 -> scatboth (row payload + col digit,
//           one pass) -> coldinv -> gather_fused (LDS counting-sort + gather
//           + epilogue in one kernel per 128-node bucket).

constexpr int NN   = 100000;
constexpr int NE   = 1600000;
constexpr int D    = 64;
constexpr int NRB  = (NN + 127) / 128;        // 782 row-buckets of 128 nodes
constexpr int NCB  = (NN + 255) / 256;        // 391 col-buckets of 256 nodes
constexpr int HB   = 256;                     // chunk-parallel grid
constexpr int HT   = 1024;
constexpr int CHUNK = NE / HB;                // 6250 (exact)
constexpr int NSR  = NRB * HB;                // 200192 row-hist elements
constexpr int NSCC = NCB * HB;                // 100096 col-hist elements
constexpr int NST  = NSR + NSCC;              // 300288 combined scan
constexpr int SCB  = 1024;
constexpr int SCG  = (NST + SCB - 1) / SCB;   // 294 scan blocks
constexpr int CAP  = 3072;                    // bucket edge cap (mean 2048, +22 sigma)

using f16x8 = __attribute__((ext_vector_type(8))) _Float16;
using f32x4 = __attribute__((ext_vector_type(4))) float;

// ---- pass 1: both bucket histograms in LDS; no global atomics ----
__global__ void __launch_bounds__(HT)
hist2_kernel(const int* __restrict__ row, const int* __restrict__ col,
             int* __restrict__ hist) {
    __shared__ int hr[NRB], hc[NCB];
    const int t = threadIdx.x;
    for (int i = t; i < NRB; i += HT) hr[i] = 0;
    for (int i = t; i < NCB; i += HT) hc[i] = 0;
    __syncthreads();
    const int e0 = blockIdx.x * CHUNK;
    for (int e = e0 + t; e < e0 + CHUNK; e += HT) {
        atomicAdd(&hr[row[e] >> 7], 1);
        atomicAdd(&hc[col[e] >> 8], 1);
    }
    __syncthreads();
    for (int i = t; i < NRB; i += HT) hist[i * HB + blockIdx.x] = hr[i];
    for (int i = t; i < NCB; i += HT) hist[NSR + i * HB + blockIdx.x] = hc[i];
}

// ---- combined exclusive scan over hist[NST] ----
__global__ void scanpart_kernel(const int* __restrict__ a, int* __restrict__ bsum) {
    __shared__ int red[16];
    const int t = threadIdx.x;
    const int i = blockIdx.x * SCB + t;
    int s = (i < NST) ? a[i] : 0;
    #pragma unroll
    for (int o = 1; o < 64; o <<= 1) s += __shfl_xor(s, o);
    if ((t & 63) == 0) red[t >> 6] = s;
    __syncthreads();
    if (t < 16) {
        int ss = red[t];
        #pragma unroll
        for (int o = 1; o < 16; o <<= 1) ss += __shfl_xor(ss, o);
        if (t == 0) bsum[blockIdx.x] = ss;
    }
}

__global__ void scanblk_kernel(const int* __restrict__ bsum, int* __restrict__ boff) {
    __shared__ int wsum[8], wsum2[8];
    const int t = threadIdx.x;          // 512
    const int lane = t & 63;
    const int w = t >> 6;               // 0..7
    const int v = (t < SCG) ? bsum[t] : 0;
    int s = v;
    #pragma unroll
    for (int o = 1; o < 64; o <<= 1) { int u = __shfl_up(s, o); if (lane >= o) s += u; }
    if (lane == 63) wsum[w] = s;
    __syncthreads();
    if (t < 8) {
        int ss = wsum[t];
        #pragma unroll
        for (int o = 1; o < 8; o <<= 1) { int u = __shfl_up(ss, o); if (t >= o) ss += u; }
        wsum2[t] = ss;
    }
    __syncthreads();
    const int excl = (w ? wsum2[w - 1] : 0) + (s - v);
    if (t < SCG) boff[t] = excl;
}

// in-place: hist -> exclusive offsets
__global__ void scanfinal_kernel(int* __restrict__ a, const int* __restrict__ boff) {
    __shared__ int wsum[16], wsum2[16];
    const int t = threadIdx.x;
    const int i = blockIdx.x * SCB + t;
    const int lane = t & 63;
    const int w = t >> 6;
    const int v = (i < NST) ? a[i] : 0;
    int s = v;
    #pragma unroll
    for (int o = 1; o < 64; o <<= 1) { int u = __shfl_up(s, o); if (lane >= o) s += u; }
    if (lane == 63) wsum[w] = s;
    __syncthreads();
    if (t < 16) {
        int ss = wsum[t];
        #pragma unroll
        for (int o = 1; o < 16; o <<= 1) { int u = __shfl_up(ss, o); if (t >= o) ss += u; }
        wsum2[t] = ss;
    }
    __syncthreads();
    const int excl = boff[blockIdx.x] + (w ? wsum2[w - 1] : 0) + (s - v);
    if (i < NST) a[i] = excl;
}

// ---- fused scatter: row payload u32 into row-buckets AND col digit byte
// into col-buckets, one pass over (row, col, dist). LDS cursors for both. ----
__global__ void __launch_bounds__(HT)
scatboth_kernel(const int* __restrict__ row, const int* __restrict__ col,
                const float* __restrict__ dist, const int* __restrict__ hoff,
                unsigned* __restrict__ payload, unsigned char* __restrict__ colidx) {
    __shared__ int cur_r[NRB];
    __shared__ int cur_c[NCB];
    const int t = threadIdx.x;
    for (int i = t; i < NRB; i += HT) cur_r[i] = hoff[i * HB + blockIdx.x];
    for (int i = t; i < NCB; i += HT) cur_c[i] = hoff[NSR + i * HB + blockIdx.x] - NE;
    __syncthreads();
    const int e0 = blockIdx.x * CHUNK;
    for (int e = e0 + t; e < e0 + CHUNK; e += HT) {
        const int r = row[e];
        const int c = col[e];
        const float dv = dist[e];
        const float wv = expf(-dv * dv);                      // (e^-1, 1]
        const unsigned w8 = (unsigned)(wv * 255.0f + 0.5f);   // 8-bit fixed pt
        const int pr = atomicAdd(&cur_r[r >> 7], 1);          // LDS atomic
        payload[pr] = ((unsigned)(r & 127) << 25) | (w8 << 17) | (unsigned)c;
        const int pc = atomicAdd(&cur_c[c >> 8], 1);          // LDS atomic
        colidx[pc] = (unsigned char)(c & 255);
    }
}

// ---- per-col-bucket exact degree count -> dinv (256 nodes/bucket) ----
__global__ void __launch_bounds__(256)
coldinv_kernel(const int* __restrict__ hoff, const unsigned char* __restrict__ colidx,
               float* __restrict__ dinv) {
    __shared__ int cnt[256];
    const int t = threadIdx.x;
    const int b = blockIdx.x;
    cnt[t] = 0;
    __syncthreads();
    const int s0 = hoff[NSR + b * HB] - NE;
    const int s1 = (b + 1 < NCB) ? (hoff[NSR + (b + 1) * HB] - NE) : NE;
    for (int k = s0 + t; k < s1; k += 256) atomicAdd(&cnt[colidx[k]], 1);
    __syncthreads();
    const int n = b * 256 + t;
    if (n < NN) {
        const int d = cnt[t];
        dinv[n] = (d > 0) ? rsqrtf((float)d) : 0.0f;
    }
}

// ---- y = x @ W^T via MFMA f16 (fp32 accumulate), y stored fp16. ----
// Per wave: W held as 8 f16x8 B-fragments (32 VGPRs, loaded once).
// A-fragment: lane holds x[n0+(lane&15)][8*(lane>>4)+i] (+32 for 2nd K-half).
// C/D: col=lane&15, row=(lane>>4)*4+reg (m89-verified layout).
__global__ void __launch_bounds__(256)
ygemm_kernel(const float* __restrict__ x, const float* __restrict__ W,
             __half* __restrict__ y) {
    const int t = threadIdx.x;
    const int m  = t & 15;
    const int kb = (t & 63) >> 4;
    f16x8 bf[4][2];
    #pragma unroll
    for (int jt = 0; jt < 4; ++jt) {
        #pragma unroll
        for (int kh = 0; kh < 2; ++kh) {
            const float* wp = W + (size_t)(jt * 16 + m) * 64 + kh * 32 + kb * 8;
            const float4 w0 = *reinterpret_cast<const float4*>(wp);
            const float4 w1 = *reinterpret_cast<const float4*>(wp + 4);
            f16x8 f;
            f[0] = (_Float16)w0.x; f[1] = (_Float16)w0.y;
            f[2] = (_Float16)w0.z; f[3] = (_Float16)w0.w;
            f[4] = (_Float16)w1.x; f[5] = (_Float16)w1.y;
            f[6] = (_Float16)w1.z; f[7] = (_Float16)w1.w;
            bf[jt][kh] = f;
        }
    }
    const int wid = (blockIdx.x * 256 + t) >> 6;
    const int nw  = (gridDim.x * 256) >> 6;
    for (int nt = wid; nt < NN / 16; nt += nw) {   // 6250 tiles exact
        const int n0 = nt * 16;
        f16x8 af[2];
        #pragma unroll
        for (int kh = 0; kh < 2; ++kh) {
            const float* xp = x + (size_t)(n0 + m) * 64 + kh * 32 + kb * 8;
            const float4 x0 = *reinterpret_cast<const float4*>(xp);
            const float4 x1 = *reinterpret_cast<const float4*>(xp + 4);
            f16x8 f;
            f[0] = (_Float16)x0.x; f[1] = (_Float16)x0.y;
            f[2] = (_Float16)x0.z; f[3] = (_Float16)x0.w;
            f[4] = (_Float16)x1.x; f[5] = (_Float16)x1.y;
            f[6] = (_Float16)x1.z; f[7] = (_Float16)x1.w;
            af[kh] = f;
        }
        #pragma unroll
        for (int jt = 0; jt < 4; ++jt) {
            f32x4 acc = {0.f, 0.f, 0.f, 0.f};
            acc = __builtin_amdgcn_mfma_f32_16x16x32_f16(af[0], bf[jt][0], acc, 0, 0, 0);
            acc = __builtin_amdgcn_mfma_f32_16x16x32_f16(af[1], bf[jt][1], acc, 0, 0, 0);
            #pragma unroll
            for (int r = 0; r < 4; ++r) {
                y[(size_t)(n0 + kb * 4 + r) * 64 + jt * 16 + m] = __float2half(acc[r]);
            }
        }
    }
}

// ---- fused counting-sort + gather + epilogue, one block per 128-node bucket.
// 512 threads = 8 waves. Stage bucket payloads in LDS, sort by digit in LDS,
// then each wave gathers 16 nodes (8 edges in flight via sub=lane>>3, 8
// channels/lane). Edge meta from LDS; y 16B/lane loads; dinv[c] from L2. ----
__global__ void __launch_bounds__(512)
gather_fused_kernel(const int* __restrict__ hoff, const unsigned* __restrict__ payload,
                    const float* __restrict__ dinvg, const __half* __restrict__ y,
                    const float* __restrict__ bias, float* __restrict__ out) {
    __shared__ unsigned stage[CAP];    // 12KB
    __shared__ unsigned sorted[CAP];   // 12KB
    __shared__ int cnt[128], cur[128], rs[129], wtot[2];
    __shared__ float dinv_s[128];
    const int t = threadIdx.x;
    const int lane = t & 63;
    const int wv = t >> 6;            // 0..7
    const int b = blockIdx.x;
    const int sub = lane >> 3;        // which of 8 concurrent edges
    const int ch8 = (lane & 7) << 3;  // 8 channels per lane
    constexpr float WSCL = 1.0f / 255.0f;
    const float4 b0 = *reinterpret_cast<const float4*>(bias + ch8);
    const float4 b1 = *reinterpret_cast<const float4*>(bias + ch8 + 4);

    if (t < 128) {
        cnt[t] = 0;
        const int n = b * 128 + t;
        dinv_s[t] = (n < NN) ? dinvg[n] : 0.0f;
    }
    const int s0g = hoff[b * HB];
    const int s1g = (b + 1 < NRB) ? hoff[(b + 1) * HB] : NE;
    int ne = s1g - s0g;
    ne = (ne < CAP) ? ne : CAP;       // impossible-overflow guard
    __syncthreads();
    for (int k = t; k < ne; k += 512) {
        const unsigned p = payload[s0g + k];
        stage[k] = p;
        atomicAdd(&cnt[p >> 25], 1);
    }
    __syncthreads();
    int s = 0, v = 0;
    if (t < 128) {                    // waves 0,1 scan the 128 counts
        v = cnt[t];
        s = v;
        #pragma unroll
        for (int o = 1; o < 64; o <<= 1) { int u = __shfl_up(s, o); if (lane >= o) s += u; }
        if (lane == 63) wtot[t >> 6] = s;
    }
    __syncthreads();
    if (t < 128) {
        const int excl = (s - v) + ((t >= 64) ? wtot[0] : 0);
        cur[t] = excl;
        rs[t] = excl;
        if (t == 0) rs[128] = wtot[0] + wtot[1];
    }
    __syncthreads();
    for (int k = t; k < ne; k += 512) {
        const unsigned p = stage[k];
        const int pos = atomicAdd(&cur[p >> 25], 1);
        sorted[pos] = p;
    }
    __syncthreads();

    for (int ln = wv; ln < 128; ln += 8) {   // 16 nodes per wave
        const int n = b * 128 + ln;
        if (n >= NN) break;                  // wave-uniform (last bucket only)
        const int e0 = rs[ln];
        const int e1 = rs[ln + 1];
        float a0 = 0.f, a1 = 0.f, a2 = 0.f, a3 = 0.f;
        float a4 = 0.f, a5 = 0.f, a6 = 0.f, a7 = 0.f;
        for (int p0 = e0; p0 < e1; p0 += 8) {
            const int pp = p0 + sub;
            const int ppc = (pp < e1) ? pp : (e1 - 1);   // clamped -> valid read
            const unsigned m = sorted[ppc];              // LDS, conflict-free
            const int c = (int)(m & 0x1FFFFu);
            float wgt = (float)((m >> 17) & 255u) * WSCL * dinvg[c];
            wgt = (pp < e1) ? wgt : 0.0f;
            const float4 raw = *reinterpret_cast<const float4*>(y + (size_t)c * 64 + ch8);
            const __half2* h2 = reinterpret_cast<const __half2*>(&raw);
            const float2 f0 = __half22float2(h2[0]);
            const float2 f1 = __half22float2(h2[1]);
            const float2 f2 = __half22float2(h2[2]);
            const float2 f3 = __half22float2(h2[3]);
            a0 += wgt * f0.x; a1 += wgt * f0.y; a2 += wgt * f1.x; a3 += wgt * f1.y;
            a4 += wgt * f2.x; a5 += wgt * f2.y; a6 += wgt * f3.x; a7 += wgt * f3.y;
        }
        #pragma unroll
        for (int o = 8; o < 64; o <<= 1) {
            a0 += __shfl_xor(a0, o); a1 += __shfl_xor(a1, o);
            a2 += __shfl_xor(a2, o); a3 += __shfl_xor(a3, o);
            a4 += __shfl_xor(a4, o); a5 += __shfl_xor(a5, o);
            a6 += __shfl_xor(a6, o); a7 += __shfl_xor(a7, o);
        }
        if (sub == 0) {
            const float dn = dinv_s[ln];
            const float4 o0 = make_float4(b0.x + dn * a0, b0.y + dn * a1,
                                          b0.z + dn * a2, b0.w + dn * a3);
            const float4 o1 = make_float4(b1.x + dn * a4, b1.y + dn * a5,
                                          b1.z + dn * a6, b1.w + dn * a7);
            float* op = out + (size_t)n * 64 + ch8;
            *reinterpret_cast<float4*>(op)     = o0;
            *reinterpret_cast<float4*>(op + 4) = o1;
        }
    }
}

extern "C" void kernel_launch(void* const* d_in, const int* in_sizes, int n_in,
                              void* d_out, int out_size, void* d_ws, size_t ws_size,
                              hipStream_t stream) {
    const float* x    = (const float*)d_in[0];
    const int*   ei   = (const int*)d_in[1];
    const float* dist = (const float*)d_in[2];
    const float* W    = (const float*)d_in[3];
    const float* b    = (const float*)d_in[4];
    float* out = (float*)d_out;

    const int* row = ei;
    const int* col = ei + NE;

    // workspace (~22.4 MB), no aliasing:
    unsigned* payload = (unsigned*)d_ws;                    // NE u32 (6.4 MB)
    __half*   y       = (__half*)(payload + NE);            // NN*64 half (12.8 MB)
    int*      hist    = (int*)(y + (size_t)NN * 64);        // NST (1.2 MB) -> hoff in place
    float*    dinv    = (float*)(hist + NST);               // NN (0.4 MB)
    int*      bsum    = (int*)(dinv + NN);                  // SCG
    int*      boff    = bsum + SCG;                         // SCG
    unsigned char* colidx = (unsigned char*)(boff + SCG);   // NE bytes (1.6 MB)

    ygemm_kernel    <<<1024, 256, 0, stream>>>(x, W, y);
    hist2_kernel    <<<HB, HT, 0, stream>>>(row, col, hist);
    scanpart_kernel <<<SCG, SCB, 0, stream>>>(hist, bsum);
    scanblk_kernel  <<<1, 512, 0, stream>>>(bsum, boff);
    scanfinal_kernel<<<SCG, SCB, 0, stream>>>(hist, boff);
    scatboth_kernel <<<HB, HT, 0, stream>>>(row, col, dist, hist, payload, colidx);
    coldinv_kernel  <<<NCB, 256, 0, stream>>>(hist, colidx, dinv);
    gather_fused_kernel<<<NRB, 512, 0, stream>>>(hist, payload, dinv, y, b, out);
}

// Round 16
// 117.479 us; speedup vs baseline: 1.7484x; 1.0261x over previous
//
#include <hip/hip_runtime.h>
#include <hip/hip_fp16.h>

// Geo_GCN, zero-global-atomic pipeline + W pulled through the edge sum:
//   out[n] = b + dinv[n] * sum_e w_e * dinv[c_e] * y[c_e],  y = x @ W^T (MFMA, fp16)
// (fp8 y tried in r15: absmax 0.047 > 0.032 -- e4m3's 3 mantissa bits too coarse.)
// Edge record = ONE u32: digit(r&63)<<25 | w8<<17 | c(17b).
// Pipeline: ygemm -> hist2 -> scanpart -> scanfinal(+prefix) -> scatboth ->
//           coldinv -> gather_fused (LDS counting-sort + gather + epilogue).

constexpr int NN   = 100000;
constexpr int NE   = 1600000;
constexpr int D    = 64;
constexpr int NRB  = (NN + 63) / 64;          // 1563 row-buckets of 64 nodes
constexpr int NCB  = (NN + 255) / 256;        // 391 col-buckets of 256 nodes
constexpr int HB   = 250;                     // chunk-parallel grid
constexpr int HT   = 1024;
constexpr int CHUNK = NE / HB;                // 6400 (exact, 16B-aligned chunks)
constexpr int NSR  = NRB * HB;                // 390750 row-hist elements
constexpr int NSCC = NCB * HB;                // 97750 col-hist elements
constexpr int NST  = NSR + NSCC;              // 488500 combined scan
constexpr int SCB  = 1024;
constexpr int SCG  = (NST + SCB - 1) / SCB;   // 478 scan blocks
constexpr int CAP  = 1536;                    // bucket edge cap (mean 1024, +16 sigma)

using f16x8 = __attribute__((ext_vector_type(8))) _Float16;
using f32x4 = __attribute__((ext_vector_type(4))) float;

// ---- pass 1: both bucket histograms in LDS; int4-vectorized edge reads ----
__global__ void __launch_bounds__(HT)
hist2_kernel(const int* __restrict__ row, const int* __restrict__ col,
             int* __restrict__ hist) {
    __shared__ int hr[NRB], hc[NCB];
    const int t = threadIdx.x;
    for (int i = t; i < NRB; i += HT) hr[i] = 0;
    for (int i = t; i < NCB; i += HT) hc[i] = 0;
    __syncthreads();
    const int e0 = blockIdx.x * CHUNK;
    for (int e = e0 + t * 4; e < e0 + CHUNK; e += HT * 4) {
        const int4 r4 = *reinterpret_cast<const int4*>(row + e);
        const int4 c4 = *reinterpret_cast<const int4*>(col + e);
        atomicAdd(&hr[r4.x >> 6], 1); atomicAdd(&hr[r4.y >> 6], 1);
        atomicAdd(&hr[r4.z >> 6], 1); atomicAdd(&hr[r4.w >> 6], 1);
        atomicAdd(&hc[c4.x >> 8], 1); atomicAdd(&hc[c4.y >> 8], 1);
        atomicAdd(&hc[c4.z >> 8], 1); atomicAdd(&hc[c4.w >> 8], 1);
    }
    __syncthreads();
    for (int i = t; i < NRB; i += HT) hist[i * HB + blockIdx.x] = hr[i];
    for (int i = t; i < NCB; i += HT) hist[NSR + i * HB + blockIdx.x] = hc[i];
}

// ---- per-scan-block sums ----
__global__ void scanpart_kernel(const int* __restrict__ a, int* __restrict__ bsum) {
    __shared__ int red[16];
    const int t = threadIdx.x;
    const int i = blockIdx.x * SCB + t;
    int s = (i < NST) ? a[i] : 0;
    #pragma unroll
    for (int o = 1; o < 64; o <<= 1) s += __shfl_xor(s, o);
    if ((t & 63) == 0) red[t >> 6] = s;
    __syncthreads();
    if (t < 16) {
        int ss = red[t];
        #pragma unroll
        for (int o = 1; o < 16; o <<= 1) ss += __shfl_xor(ss, o);
        if (t == 0) bsum[blockIdx.x] = ss;
    }
}

// in-place final scan; block prefix computed here from bsum (no scanblk kernel)
__global__ void scanfinal_kernel(int* __restrict__ a, const int* __restrict__ bsum) {
    __shared__ int wsum[16], wsum2[16], red[16];
    __shared__ int prefix_s;
    const int t = threadIdx.x;
    const int i = blockIdx.x * SCB + t;
    const int lane = t & 63;
    const int w = t >> 6;
    // prefix over bsum[0 .. blockIdx.x)
    int pv = (t < blockIdx.x) ? bsum[t] : 0;   // blockIdx < SCG=478 < 1024
    #pragma unroll
    for (int o = 1; o < 64; o <<= 1) pv += __shfl_xor(pv, o);
    if (lane == 0) red[w] = pv;
    // per-element wave scan
    const int v = (i < NST) ? a[i] : 0;
    int s = v;
    #pragma unroll
    for (int o = 1; o < 64; o <<= 1) { int u = __shfl_up(s, o); if (lane >= o) s += u; }
    if (lane == 63) wsum[w] = s;
    __syncthreads();
    if (t < 16) {
        int ss = wsum[t];
        #pragma unroll
        for (int o = 1; o < 16; o <<= 1) { int u = __shfl_up(ss, o); if (t >= o) ss += u; }
        wsum2[t] = ss;
        int rr = red[t];
        #pragma unroll
        for (int o = 1; o < 16; o <<= 1) rr += __shfl_xor(rr, o);
        if (t == 0) prefix_s = rr;
    }
    __syncthreads();
    const int excl = prefix_s + (w ? wsum2[w - 1] : 0) + (s - v);
    if (i < NST) a[i] = excl;
}

// ---- fused scatter: row payload u32 + col digit byte, one vectorized pass ----
__global__ void __launch_bounds__(HT)
scatboth_kernel(const int* __restrict__ row, const int* __restrict__ col,
                const float* __restrict__ dist, const int* __restrict__ hoff,
                unsigned* __restrict__ payload, unsigned char* __restrict__ colidx) {
    __shared__ int cur_r[NRB];
    __shared__ int cur_c[NCB];
    const int t = threadIdx.x;
    for (int i = t; i < NRB; i += HT) cur_r[i] = hoff[i * HB + blockIdx.x];
    for (int i = t; i < NCB; i += HT) cur_c[i] = hoff[NSR + i * HB + blockIdx.x] - NE;
    __syncthreads();
    const int e0 = blockIdx.x * CHUNK;
    for (int e = e0 + t * 4; e < e0 + CHUNK; e += HT * 4) {
        const int4 r4 = *reinterpret_cast<const int4*>(row + e);
        const int4 c4 = *reinterpret_cast<const int4*>(col + e);
        const float4 d4 = *reinterpret_cast<const float4*>(dist + e);
        const int rr[4] = {r4.x, r4.y, r4.z, r4.w};
        const int cc[4] = {c4.x, c4.y, c4.z, c4.w};
        const float dd[4] = {d4.x, d4.y, d4.z, d4.w};
        #pragma unroll
        for (int j = 0; j < 4; ++j) {
            const int r = rr[j];
            const int c = cc[j];
            const float dv = dd[j];
            const unsigned w8 = (unsigned)(__expf(-dv * dv) * 255.0f + 0.5f);
            const int pr = atomicAdd(&cur_r[r >> 6], 1);
            payload[pr] = ((unsigned)(r & 63) << 25) | (w8 << 17) | (unsigned)c;
            const int pc = atomicAdd(&cur_c[c >> 8], 1);
            colidx[pc] = (unsigned char)(c & 255);
        }
    }
}

// ---- per-col-bucket exact degree count -> dinv (256 nodes/bucket) ----
__global__ void __launch_bounds__(256)
coldinv_kernel(const int* __restrict__ hoff, const unsigned char* __restrict__ colidx,
               float* __restrict__ dinv) {
    __shared__ int cnt[256];
    const int t = threadIdx.x;
    const int b = blockIdx.x;
    cnt[t] = 0;
    __syncthreads();
    const int s0 = hoff[NSR + b * HB] - NE;
    const int s1 = (b + 1 < NCB) ? (hoff[NSR + (b + 1) * HB] - NE) : NE;
    for (int k = s0 + t; k < s1; k += 256) atomicAdd(&cnt[colidx[k]], 1);
    __syncthreads();
    const int n = b * 256 + t;
    if (n < NN) {
        const int d = cnt[t];
        dinv[n] = (d > 0) ? rsqrtf((float)d) : 0.0f;
    }
}

// ---- y = x @ W^T via MFMA (A=W, B=x): lane owns node n0+(lane&15), channels
// jt*16 + kb*4 + r (consecutive!) -> packed 8B fp16 stores. ----
__global__ void __launch_bounds__(256)
ygemm_kernel(const float* __restrict__ x, const float* __restrict__ W,
             __half* __restrict__ y) {
    const int t = threadIdx.x;
    const int m  = t & 15;
    const int kb = (t & 63) >> 4;
    f16x8 bf[4][2];
    #pragma unroll
    for (int jt = 0; jt < 4; ++jt) {
        #pragma unroll
        for (int kh = 0; kh < 2; ++kh) {
            const float* wp = W + (size_t)(jt * 16 + m) * 64 + kh * 32 + kb * 8;
            const float4 w0 = *reinterpret_cast<const float4*>(wp);
            const float4 w1 = *reinterpret_cast<const float4*>(wp + 4);
            f16x8 f;
            f[0] = (_Float16)w0.x; f[1] = (_Float16)w0.y;
            f[2] = (_Float16)w0.z; f[3] = (_Float16)w0.w;
            f[4] = (_Float16)w1.x; f[5] = (_Float16)w1.y;
            f[6] = (_Float16)w1.z; f[7] = (_Float16)w1.w;
            bf[jt][kh] = f;
        }
    }
    const int wid = (blockIdx.x * 256 + t) >> 6;
    const int nw  = (gridDim.x * 256) >> 6;
    for (int nt = wid; nt < NN / 16; nt += nw) {   // 6250 tiles exact
        const int n0 = nt * 16;
        f16x8 af[2];
        #pragma unroll
        for (int kh = 0; kh < 2; ++kh) {
            const float* xp = x + (size_t)(n0 + m) * 64 + kh * 32 + kb * 8;
            const float4 x0 = *reinterpret_cast<const float4*>(xp);
            const float4 x1 = *reinterpret_cast<const float4*>(xp + 4);
            f16x8 f;
            f[0] = (_Float16)x0.x; f[1] = (_Float16)x0.y;
            f[2] = (_Float16)x0.z; f[3] = (_Float16)x0.w;
            f[4] = (_Float16)x1.x; f[5] = (_Float16)x1.y;
            f[6] = (_Float16)x1.z; f[7] = (_Float16)x1.w;
            af[kh] = f;
        }
        #pragma unroll
        for (int jt = 0; jt < 4; ++jt) {
            f32x4 acc = {0.f, 0.f, 0.f, 0.f};
            // A = W (bf), B = x (af): C[ch][node]; lane m = node, rows = channels
            acc = __builtin_amdgcn_mfma_f32_16x16x32_f16(bf[jt][0], af[0], acc, 0, 0, 0);
            acc = __builtin_amdgcn_mfma_f32_16x16x32_f16(bf[jt][1], af[1], acc, 0, 0, 0);
            const size_t elem = (size_t)(n0 + m) * 64 + jt * 16 + kb * 4;
            union { uint2 u; __half h[4]; } pk;
            pk.h[0] = __float2half(acc[0]); pk.h[1] = __float2half(acc[1]);
            pk.h[2] = __float2half(acc[2]); pk.h[3] = __float2half(acc[3]);
            *reinterpret_cast<uint2*>(y + elem) = pk.u;
        }
    }
}

// ---- fused counting-sort + gather + epilogue, one block per 64-node bucket.
// 256 threads = 4 waves; each wave gathers 16 nodes, 8 edges in flight. ----
__global__ void __launch_bounds__(256)
gather_fused_kernel(const int* __restrict__ hoff, const unsigned* __restrict__ payload,
                    const float* __restrict__ dinvg, const __half* __restrict__ y,
                    const float* __restrict__ bias, float* __restrict__ out) {
    __shared__ unsigned stage[CAP];    // 6KB
    __shared__ unsigned sorted[CAP];   // 6KB
    __shared__ int cnt[64], cur[64], rs[65];
    __shared__ float dinv_s[64];
    const int t = threadIdx.x;
    const int lane = t & 63;
    const int wv = t >> 6;            // 0..3
    const int b = blockIdx.x;
    const int sub = lane >> 3;        // which of 8 concurrent edges
    const int ch8 = (lane & 7) << 3;  // 8 channels per lane
    constexpr float WSCL = 1.0f / 255.0f;
    const float4 b0 = *reinterpret_cast<const float4*>(bias + ch8);
    const float4 b1 = *reinterpret_cast<const float4*>(bias + ch8 + 4);

    if (t < 64) {
        cnt[t] = 0;
        const int n = b * 64 + t;
        dinv_s[t] = (n < NN) ? dinvg[n] : 0.0f;
    }
    const int s0g = hoff[b * HB];
    const int s1g = (b + 1 < NRB) ? hoff[(b + 1) * HB] : NE;
    int ne = s1g - s0g;
    ne = (ne < CAP) ? ne : CAP;       // impossible-overflow guard
    __syncthreads();
    for (int k = t; k < ne; k += 256) {
        const unsigned p = payload[s0g + k];
        stage[k] = p;
        atomicAdd(&cnt[p >> 25], 1);
    }
    __syncthreads();
    if (t < 64) {                     // wave 0 scans the 64 counts
        const int v = cnt[t];
        int s = v;
        #pragma unroll
        for (int o = 1; o < 64; o <<= 1) { int u = __shfl_up(s, o); if (t >= o) s += u; }
        cur[t] = s - v;
        rs[t] = s - v;
        if (t == 63) rs[64] = s;
    }
    __syncthreads();
    for (int k = t; k < ne; k += 256) {
        const unsigned p = stage[k];
        const int pos = atomicAdd(&cur[p >> 25], 1);
        sorted[pos] = p;
    }
    __syncthreads();

    for (int ln = wv; ln < 64; ln += 4) {    // 16 nodes per wave
        const int n = b * 64 + ln;
        if (n >= NN) break;                  // wave-uniform (last bucket only)
        const int e0 = rs[ln];
        const int e1 = rs[ln + 1];
        float a0 = 0.f, a1 = 0.f, a2 = 0.f, a3 = 0.f;
        float a4 = 0.f, a5 = 0.f, a6 = 0.f, a7 = 0.f;
        for (int p0 = e0; p0 < e1; p0 += 8) {
            const int pp = p0 + sub;
            const int ppc = (pp < e1) ? pp : (e1 - 1);   // clamped -> valid read
            const unsigned m = sorted[ppc];
            const int c = (int)(m & 0x1FFFFu);
            float wgt = (float)((m >> 17) & 255u) * WSCL * dinvg[c];
            wgt = (pp < e1) ? wgt : 0.0f;
            const float4 raw = *reinterpret_cast<const float4*>(y + (size_t)c * 64 + ch8);
            const __half2* h2 = reinterpret_cast<const __half2*>(&raw);
            const float2 f0 = __half22float2(h2[0]);
            const float2 f1 = __half22float2(h2[1]);
            const float2 f2 = __half22float2(h2[2]);
            const float2 f3 = __half22float2(h2[3]);
            a0 += wgt * f0.x; a1 += wgt * f0.y; a2 += wgt * f1.x; a3 += wgt * f1.y;
            a4 += wgt * f2.x; a5 += wgt * f2.y; a6 += wgt * f3.x; a7 += wgt * f3.y;
        }
        #pragma unroll
        for (int o = 8; o < 64; o <<= 1) {
            a0 += __shfl_xor(a0, o); a1 += __shfl_xor(a1, o);
            a2 += __shfl_xor(a2, o); a3 += __shfl_xor(a3, o);
            a4 += __shfl_xor(a4, o); a5 += __shfl_xor(a5, o);
            a6 += __shfl_xor(a6, o); a7 += __shfl_xor(a7, o);
        }
        if (sub == 0) {
            const float dn = dinv_s[ln];
            const float4 o0 = make_float4(b0.x + dn * a0, b0.y + dn * a1,
                                          b0.z + dn * a2, b0.w + dn * a3);
            const float4 o1 = make_float4(b1.x + dn * a4, b1.y + dn * a5,
                                          b1.z + dn * a6, b1.w + dn * a7);
            float* op = out + (size_t)n * 64 + ch8;
            *reinterpret_cast<float4*>(op)     = o0;
            *reinterpret_cast<float4*>(op + 4) = o1;
        }
    }
}

extern "C" void kernel_launch(void* const* d_in, const int* in_sizes, int n_in,
                              void* d_out, int out_size, void* d_ws, size_t ws_size,
                              hipStream_t stream) {
    const float* x    = (const float*)d_in[0];
    const int*   ei   = (const int*)d_in[1];
    const float* dist = (const float*)d_in[2];
    const float* W    = (const float*)d_in[3];
    const float* b    = (const float*)d_in[4];
    float* out = (float*)d_out;

    const int* row = ei;
    const int* col = ei + NE;

    // workspace (~23.2 MB)
    unsigned*      payload = (unsigned*)d_ws;                   // NE u32 (6.4 MB)
    __half*        y       = (__half*)(payload + NE);           // NN*64 fp16 (12.8 MB)
    int*           hist    = (int*)(y + (size_t)NN * 64);       // NST (1.95 MB)
    int*           bsum    = hist + NST;                        // SCG
    unsigned char* colidx  = (unsigned char*)(bsum + SCG);      // NE bytes (1.6 MB)
    float*         dinv    = (float*)(colidx + NE);             // NN (0.4 MB)

    ygemm_kernel    <<<1024, 256, 0, stream>>>(x, W, y);
    hist2_kernel    <<<HB, HT, 0, stream>>>(row, col, hist);
    scanpart_kernel <<<SCG, SCB, 0, stream>>>(hist, bsum);
    scanfinal_kernel<<<SCG, SCB, 0, stream>>>(hist, bsum);
    scatboth_kernel <<<HB, HT, 0, stream>>>(row, col, dist, hist, payload, colidx);
    coldinv_kernel  <<<NCB, 256, 0, stream>>>(hist, colidx, dinv);
    gather_fused_kernel<<<NRB, 256, 0, stream>>>(hist, payload, dinv, y, b, out);
}

// Round 17
// 114.283 us; speedup vs baseline: 1.7973x; 1.0280x over previous
//
#include <hip/hip_runtime.h>
#include <hip/hip_fp16.h>

// Geo_GCN, zero-global-atomic pipeline + W pulled through the edge sum:
//   out[n] = b + dinv[n] * sum_e w_e * dinv[c_e] * y[c_e],  y = x @ W^T (MFMA, fp16)
// Edge record = ONE u32: digit(r&63)<<25 | w8<<17 | c(17b).
// Pipeline: prep (ygemm || hist2, block-partitioned) -> scanpart ->
//           scanfinal(+prefix) -> scatboth -> coldinv -> gather_fused.

constexpr int NN   = 100000;
constexpr int NE   = 1600000;
constexpr int D    = 64;
constexpr int NRB  = (NN + 63) / 64;          // 1563 row-buckets of 64 nodes
constexpr int NCB  = (NN + 255) / 256;        // 391 col-buckets of 256 nodes
constexpr int HB   = 250;                     // hist/scatter chunk grid
constexpr int HT   = 1024;                    // scatboth block size
constexpr int PT   = 512;                     // prep block size
constexpr int YGB  = 512;                     // ygemm blocks inside prep
constexpr int CHUNK = NE / HB;                // 6400 (exact, 16B-aligned chunks)
constexpr int NSR  = NRB * HB;                // 390750 row-hist elements
constexpr int NSCC = NCB * HB;                // 97750 col-hist elements
constexpr int NST  = NSR + NSCC;              // 488500 combined scan
constexpr int SCB  = 1024;
constexpr int SCG  = (NST + SCB - 1) / SCB;   // 478 scan blocks
constexpr int CAP  = 1536;                    // bucket edge cap (mean 1024, +16 sigma)

using f16x8 = __attribute__((ext_vector_type(8))) _Float16;
using f32x4 = __attribute__((ext_vector_type(4))) float;

// ---- pass 1: FUSED ygemm (MFMA) || hist2 (LDS histograms), block-partitioned.
// Blocks [0,HB): histogram row>>6 / col>>8 of their edge chunk (int4 reads).
// Blocks [HB,HB+YGB): y = x @ W^T, A=W B=x operand order -> lane owns one
// node's 4 consecutive channels per acc reg -> packed 8B fp16 stores.
__global__ void __launch_bounds__(PT)
prep_kernel(const float* __restrict__ x, const float* __restrict__ W,
            __half* __restrict__ y, const int* __restrict__ row,
            const int* __restrict__ col, int* __restrict__ hist) {
    __shared__ int hr[NRB], hc[NCB];
    const int t = threadIdx.x;
    const int blk = blockIdx.x;
    if (blk < HB) {
        // ---------------- hist2 part ----------------
        for (int i = t; i < NRB; i += PT) hr[i] = 0;
        for (int i = t; i < NCB; i += PT) hc[i] = 0;
        __syncthreads();
        const int e0 = blk * CHUNK;
        for (int e = e0 + t * 4; e < e0 + CHUNK; e += PT * 4) {
            const int4 r4 = *reinterpret_cast<const int4*>(row + e);
            const int4 c4 = *reinterpret_cast<const int4*>(col + e);
            atomicAdd(&hr[r4.x >> 6], 1); atomicAdd(&hr[r4.y >> 6], 1);
            atomicAdd(&hr[r4.z >> 6], 1); atomicAdd(&hr[r4.w >> 6], 1);
            atomicAdd(&hc[c4.x >> 8], 1); atomicAdd(&hc[c4.y >> 8], 1);
            atomicAdd(&hc[c4.z >> 8], 1); atomicAdd(&hc[c4.w >> 8], 1);
        }
        __syncthreads();
        for (int i = t; i < NRB; i += PT) hist[i * HB + blk] = hr[i];
        for (int i = t; i < NCB; i += PT) hist[NSR + i * HB + blk] = hc[i];
    } else {
        // ---------------- ygemm part ----------------
        const int m  = t & 15;
        const int kb = (t & 63) >> 4;
        f16x8 bf[4][2];
        #pragma unroll
        for (int jt = 0; jt < 4; ++jt) {
            #pragma unroll
            for (int kh = 0; kh < 2; ++kh) {
                const float* wp = W + (size_t)(jt * 16 + m) * 64 + kh * 32 + kb * 8;
                const float4 w0 = *reinterpret_cast<const float4*>(wp);
                const float4 w1 = *reinterpret_cast<const float4*>(wp + 4);
                f16x8 f;
                f[0] = (_Float16)w0.x; f[1] = (_Float16)w0.y;
                f[2] = (_Float16)w0.z; f[3] = (_Float16)w0.w;
                f[4] = (_Float16)w1.x; f[5] = (_Float16)w1.y;
                f[6] = (_Float16)w1.z; f[7] = (_Float16)w1.w;
                bf[jt][kh] = f;
            }
        }
        const int wid = ((blk - HB) * PT + t) >> 6;
        const int nw  = (YGB * PT) >> 6;       // 4096 waves
        for (int nt = wid; nt < NN / 16; nt += nw) {   // 6250 tiles exact
            const int n0 = nt * 16;
            f16x8 af[2];
            #pragma unroll
            for (int kh = 0; kh < 2; ++kh) {
                const float* xp = x + (size_t)(n0 + m) * 64 + kh * 32 + kb * 8;
                const float4 x0 = *reinterpret_cast<const float4*>(xp);
                const float4 x1 = *reinterpret_cast<const float4*>(xp + 4);
                f16x8 f;
                f[0] = (_Float16)x0.x; f[1] = (_Float16)x0.y;
                f[2] = (_Float16)x0.z; f[3] = (_Float16)x0.w;
                f[4] = (_Float16)x1.x; f[5] = (_Float16)x1.y;
                f[6] = (_Float16)x1.z; f[7] = (_Float16)x1.w;
                af[kh] = f;
            }
            #pragma unroll
            for (int jt = 0; jt < 4; ++jt) {
                f32x4 acc = {0.f, 0.f, 0.f, 0.f};
                acc = __builtin_amdgcn_mfma_f32_16x16x32_f16(bf[jt][0], af[0], acc, 0, 0, 0);
                acc = __builtin_amdgcn_mfma_f32_16x16x32_f16(bf[jt][1], af[1], acc, 0, 0, 0);
                const size_t elem = (size_t)(n0 + m) * 64 + jt * 16 + kb * 4;
                union { uint2 u; __half h[4]; } pk;
                pk.h[0] = __float2half(acc[0]); pk.h[1] = __float2half(acc[1]);
                pk.h[2] = __float2half(acc[2]); pk.h[3] = __float2half(acc[3]);
                *reinterpret_cast<uint2*>(y + elem) = pk.u;
            }
        }
    }
}

// ---- per-scan-block sums ----
__global__ void scanpart_kernel(const int* __restrict__ a, int* __restrict__ bsum) {
    __shared__ int red[16];
    const int t = threadIdx.x;
    const int i = blockIdx.x * SCB + t;
    int s = (i < NST) ? a[i] : 0;
    #pragma unroll
    for (int o = 1; o < 64; o <<= 1) s += __shfl_xor(s, o);
    if ((t & 63) == 0) red[t >> 6] = s;
    __syncthreads();
    if (t < 16) {
        int ss = red[t];
        #pragma unroll
        for (int o = 1; o < 16; o <<= 1) ss += __shfl_xor(ss, o);
        if (t == 0) bsum[blockIdx.x] = ss;
    }
}

// in-place final scan; block prefix computed here from bsum (no scanblk kernel)
__global__ void scanfinal_kernel(int* __restrict__ a, const int* __restrict__ bsum) {
    __shared__ int wsum[16], wsum2[16], red[16];
    __shared__ int prefix_s;
    const int t = threadIdx.x;
    const int i = blockIdx.x * SCB + t;
    const int lane = t & 63;
    const int w = t >> 6;
    // prefix over bsum[0 .. blockIdx.x)
    int pv = (t < blockIdx.x) ? bsum[t] : 0;   // blockIdx < SCG=478 < 1024
    #pragma unroll
    for (int o = 1; o < 64; o <<= 1) pv += __shfl_xor(pv, o);
    if (lane == 0) red[w] = pv;
    // per-element wave scan
    const int v = (i < NST) ? a[i] : 0;
    int s = v;
    #pragma unroll
    for (int o = 1; o < 64; o <<= 1) { int u = __shfl_up(s, o); if (lane >= o) s += u; }
    if (lane == 63) wsum[w] = s;
    __syncthreads();
    if (t < 16) {
        int ss = wsum[t];
        #pragma unroll
        for (int o = 1; o < 16; o <<= 1) { int u = __shfl_up(ss, o); if (t >= o) ss += u; }
        wsum2[t] = ss;
        int rr = red[t];
        #pragma unroll
        for (int o = 1; o < 16; o <<= 1) rr += __shfl_xor(rr, o);
        if (t == 0) prefix_s = rr;
    }
    __syncthreads();
    const int excl = prefix_s + (w ? wsum2[w - 1] : 0) + (s - v);
    if (i < NST) a[i] = excl;
}

// ---- fused scatter: row payload u32 + col digit byte, one vectorized pass ----
__global__ void __launch_bounds__(HT)
scatboth_kernel(const int* __restrict__ row, const int* __restrict__ col,
                const float* __restrict__ dist, const int* __restrict__ hoff,
                unsigned* __restrict__ payload, unsigned char* __restrict__ colidx) {
    __shared__ int cur_r[NRB];
    __shared__ int cur_c[NCB];
    const int t = threadIdx.x;
    for (int i = t; i < NRB; i += HT) cur_r[i] = hoff[i * HB + blockIdx.x];
    for (int i = t; i < NCB; i += HT) cur_c[i] = hoff[NSR + i * HB + blockIdx.x] - NE;
    __syncthreads();
    const int e0 = blockIdx.x * CHUNK;
    for (int e = e0 + t * 4; e < e0 + CHUNK; e += HT * 4) {
        const int4 r4 = *reinterpret_cast<const int4*>(row + e);
        const int4 c4 = *reinterpret_cast<const int4*>(col + e);
        const float4 d4 = *reinterpret_cast<const float4*>(dist + e);
        const int rr[4] = {r4.x, r4.y, r4.z, r4.w};
        const int cc[4] = {c4.x, c4.y, c4.z, c4.w};
        const float dd[4] = {d4.x, d4.y, d4.z, d4.w};
        #pragma unroll
        for (int j = 0; j < 4; ++j) {
            const int r = rr[j];
            const int c = cc[j];
            const float dv = dd[j];
            const unsigned w8 = (unsigned)(__expf(-dv * dv) * 255.0f + 0.5f);
            const int pr = atomicAdd(&cur_r[r >> 6], 1);
            payload[pr] = ((unsigned)(r & 63) << 25) | (w8 << 17) | (unsigned)c;
            const int pc = atomicAdd(&cur_c[c >> 8], 1);
            colidx[pc] = (unsigned char)(c & 255);
        }
    }
}

// ---- per-col-bucket exact degree count -> dinv (256 nodes/bucket) ----
__global__ void __launch_bounds__(256)
coldinv_kernel(const int* __restrict__ hoff, const unsigned char* __restrict__ colidx,
               float* __restrict__ dinv) {
    __shared__ int cnt[256];
    const int t = threadIdx.x;
    const int b = blockIdx.x;
    cnt[t] = 0;
    __syncthreads();
    const int s0 = hoff[NSR + b * HB] - NE;
    const int s1 = (b + 1 < NCB) ? (hoff[NSR + (b + 1) * HB] - NE) : NE;
    for (int k = s0 + t; k < s1; k += 256) atomicAdd(&cnt[colidx[k]], 1);
    __syncthreads();
    const int n = b * 256 + t;
    if (n < NN) {
        const int d = cnt[t];
        dinv[n] = (d > 0) ? rsqrtf((float)d) : 0.0f;
    }
}

// ---- fused counting-sort + gather + epilogue, one block per 64-node bucket.
// 256 threads = 4 waves; each wave gathers 16 nodes, 8 edges in flight. ----
__global__ void __launch_bounds__(256)
gather_fused_kernel(const int* __restrict__ hoff, const unsigned* __restrict__ payload,
                    const float* __restrict__ dinvg, const __half* __restrict__ y,
                    const float* __restrict__ bias, float* __restrict__ out) {
    __shared__ unsigned stage[CAP];    // 6KB
    __shared__ unsigned sorted[CAP];   // 6KB
    __shared__ int cnt[64], cur[64], rs[65];
    __shared__ float dinv_s[64];
    const int t = threadIdx.x;
    const int lane = t & 63;
    const int wv = t >> 6;            // 0..3
    const int b = blockIdx.x;
    const int sub = lane >> 3;        // which of 8 concurrent edges
    const int ch8 = (lane & 7) << 3;  // 8 channels per lane
    constexpr float WSCL = 1.0f / 255.0f;
    const float4 b0 = *reinterpret_cast<const float4*>(bias + ch8);
    const float4 b1 = *reinterpret_cast<const float4*>(bias + ch8 + 4);

    if (t < 64) {
        cnt[t] = 0;
        const int n = b * 64 + t;
        dinv_s[t] = (n < NN) ? dinvg[n] : 0.0f;
    }
    const int s0g = hoff[b * HB];
    const int s1g = (b + 1 < NRB) ? hoff[(b + 1) * HB] : NE;
    int ne = s1g - s0g;
    ne = (ne < CAP) ? ne : CAP;       // impossible-overflow guard
    __syncthreads();
    for (int k = t; k < ne; k += 256) {
        const unsigned p = payload[s0g + k];
        stage[k] = p;
        atomicAdd(&cnt[p >> 25], 1);
    }
    __syncthreads();
    if (t < 64) {                     // wave 0 scans the 64 counts
        const int v = cnt[t];
        int s = v;
        #pragma unroll
        for (int o = 1; o < 64; o <<= 1) { int u = __shfl_up(s, o); if (t >= o) s += u; }
        cur[t] = s - v;
        rs[t] = s - v;
        if (t == 63) rs[64] = s;
    }
    __syncthreads();
    for (int k = t; k < ne; k += 256) {
        const unsigned p = stage[k];
        const int pos = atomicAdd(&cur[p >> 25], 1);
        sorted[pos] = p;
    }
    __syncthreads();

    for (int ln = wv; ln < 64; ln += 4) {    // 16 nodes per wave
        const int n = b * 64 + ln;
        if (n >= NN) break;                  // wave-uniform (last bucket only)
        const int e0 = rs[ln];
        const int e1 = rs[ln + 1];
        float a0 = 0.f, a1 = 0.f, a2 = 0.f, a3 = 0.f;
        float a4 = 0.f, a5 = 0.f, a6 = 0.f, a7 = 0.f;
        for (int p0 = e0; p0 < e1; p0 += 8) {
            const int pp = p0 + sub;
            const int ppc = (pp < e1) ? pp : (e1 - 1);   // clamped -> valid read
            const unsigned m = sorted[ppc];
            const int c = (int)(m & 0x1FFFFu);
            float wgt = (float)((m >> 17) & 255u) * WSCL * dinvg[c];
            wgt = (pp < e1) ? wgt : 0.0f;
            const float4 raw = *reinterpret_cast<const float4*>(y + (size_t)c * 64 + ch8);
            const __half2* h2 = reinterpret_cast<const __half2*>(&raw);
            const float2 f0 = __half22float2(h2[0]);
            const float2 f1 = __half22float2(h2[1]);
            const float2 f2 = __half22float2(h2[2]);
            const float2 f3 = __half22float2(h2[3]);
            a0 += wgt * f0.x; a1 += wgt * f0.y; a2 += wgt * f1.x; a3 += wgt * f1.y;
            a4 += wgt * f2.x; a5 += wgt * f2.y; a6 += wgt * f3.x; a7 += wgt * f3.y;
        }
        #pragma unroll
        for (int o = 8; o < 64; o <<= 1) {
            a0 += __shfl_xor(a0, o); a1 += __shfl_xor(a1, o);
            a2 += __shfl_xor(a2, o); a3 += __shfl_xor(a3, o);
            a4 += __shfl_xor(a4, o); a5 += __shfl_xor(a5, o);
            a6 += __shfl_xor(a6, o); a7 += __shfl_xor(a7, o);
        }
        if (sub == 0) {
            const float dn = dinv_s[ln];
            const float4 o0 = make_float4(b0.x + dn * a0, b0.y + dn * a1,
                                          b0.z + dn * a2, b0.w + dn * a3);
            const float4 o1 = make_float4(b1.x + dn * a4, b1.y + dn * a5,
                                          b1.z + dn * a6, b1.w + dn * a7);
            float* op = out + (size_t)n * 64 + ch8;
            *reinterpret_cast<float4*>(op)     = o0;
            *reinterpret_cast<float4*>(op + 4) = o1;
        }
    }
}

extern "C" void kernel_launch(void* const* d_in, const int* in_sizes, int n_in,
                              void* d_out, int out_size, void* d_ws, size_t ws_size,
                              hipStream_t stream) {
    const float* x    = (const float*)d_in[0];
    const int*   ei   = (const int*)d_in[1];
    const float* dist = (const float*)d_in[2];
    const float* W    = (const float*)d_in[3];
    const float* b    = (const float*)d_in[4];
    float* out = (float*)d_out;

    const int* row = ei;
    const int* col = ei + NE;

    // workspace (~23.2 MB)
    unsigned*      payload = (unsigned*)d_ws;                   // NE u32 (6.4 MB)
    __half*        y       = (__half*)(payload + NE);           // NN*64 fp16 (12.8 MB)
    int*           hist    = (int*)(y + (size_t)NN * 64);       // NST (1.95 MB)
    int*           bsum    = hist + NST;                        // SCG
    unsigned char* colidx  = (unsigned char*)(bsum + SCG);      // NE bytes (1.6 MB)
    float*         dinv    = (float*)(colidx + NE);             // NN (0.4 MB)

    prep_kernel     <<<HB + YGB, PT, 0, stream>>>(x, W, y, row, col, hist);
    scanpart_kernel <<<SCG, SCB, 0, stream>>>(hist, bsum);
    scanfinal_kernel<<<SCG, SCB, 0, stream>>>(hist, bsum);
    scatboth_kernel <<<HB, HT, 0, stream>>>(row, col, dist, hist, payload, colidx);
    coldinv_kernel  <<<NCB, 256, 0, stream>>>(hist, colidx, dinv);
    gather_fused_kernel<<<NRB, 256, 0, stream>>>(hist, payload, dinv, y, b, out);
}

// Round 18
// 111.964 us; speedup vs baseline: 1.8345x; 1.0207x over previous
//
#include <hip/hip_runtime.h>
#include <hip/hip_fp16.h>

// Geo_GCN, zero-global-atomic pipeline + W pulled through the edge sum:
//   out[n] = b + dinv[n] * sum_e w_e * dinv[c_e] * y[c_e],  y = x @ W^T (MFMA, fp16)
// Edge record = ONE u32: digit(r&63)<<25 | w8<<17 | c(17b).
// Pipeline: prep (ygemm || hist2, block-partitioned) -> scanpart ->
//           scanfinal(+prefix) -> scatboth -> coldinv -> gather_fused(512thr).

constexpr int NN   = 100000;
constexpr int NE   = 1600000;
constexpr int D    = 64;
constexpr int NRB  = (NN + 63) / 64;          // 1563 row-buckets of 64 nodes
constexpr int NCB  = (NN + 255) / 256;        // 391 col-buckets of 256 nodes
constexpr int HB   = 250;                     // hist/scatter chunk grid
constexpr int HT   = 1024;                    // scatboth block size
constexpr int PT   = 512;                     // prep block size
constexpr int YGB  = 512;                     // ygemm blocks inside prep
constexpr int GT   = 512;                     // gather block size (8 waves)
constexpr int CHUNK = NE / HB;                // 6400 (exact, 16B-aligned chunks)
constexpr int NSR  = NRB * HB;                // 390750 row-hist elements
constexpr int NSCC = NCB * HB;                // 97750 col-hist elements
constexpr int NST  = NSR + NSCC;              // 488500 combined scan
constexpr int SCB  = 1024;
constexpr int SCG  = (NST + SCB - 1) / SCB;   // 478 scan blocks
constexpr int CAP  = 1536;                    // bucket edge cap (mean 1024, +16 sigma)

using f16x8 = __attribute__((ext_vector_type(8))) _Float16;
using f32x4 = __attribute__((ext_vector_type(4))) float;

// ---- pass 1: FUSED ygemm (MFMA) || hist2 (LDS histograms), block-partitioned.
__global__ void __launch_bounds__(PT)
prep_kernel(const float* __restrict__ x, const float* __restrict__ W,
            __half* __restrict__ y, const int* __restrict__ row,
            const int* __restrict__ col, int* __restrict__ hist) {
    __shared__ int hr[NRB], hc[NCB];
    const int t = threadIdx.x;
    const int blk = blockIdx.x;
    if (blk < HB) {
        // ---------------- hist2 part ----------------
        for (int i = t; i < NRB; i += PT) hr[i] = 0;
        for (int i = t; i < NCB; i += PT) hc[i] = 0;
        __syncthreads();
        const int e0 = blk * CHUNK;
        for (int e = e0 + t * 4; e < e0 + CHUNK; e += PT * 4) {
            const int4 r4 = *reinterpret_cast<const int4*>(row + e);
            const int4 c4 = *reinterpret_cast<const int4*>(col + e);
            atomicAdd(&hr[r4.x >> 6], 1); atomicAdd(&hr[r4.y >> 6], 1);
            atomicAdd(&hr[r4.z >> 6], 1); atomicAdd(&hr[r4.w >> 6], 1);
            atomicAdd(&hc[c4.x >> 8], 1); atomicAdd(&hc[c4.y >> 8], 1);
            atomicAdd(&hc[c4.z >> 8], 1); atomicAdd(&hc[c4.w >> 8], 1);
        }
        __syncthreads();
        for (int i = t; i < NRB; i += PT) hist[i * HB + blk] = hr[i];
        for (int i = t; i < NCB; i += PT) hist[NSR + i * HB + blk] = hc[i];
    } else {
        // ---------------- ygemm part ----------------
        const int m  = t & 15;
        const int kb = (t & 63) >> 4;
        f16x8 bf[4][2];
        #pragma unroll
        for (int jt = 0; jt < 4; ++jt) {
            #pragma unroll
            for (int kh = 0; kh < 2; ++kh) {
                const float* wp = W + (size_t)(jt * 16 + m) * 64 + kh * 32 + kb * 8;
                const float4 w0 = *reinterpret_cast<const float4*>(wp);
                const float4 w1 = *reinterpret_cast<const float4*>(wp + 4);
                f16x8 f;
                f[0] = (_Float16)w0.x; f[1] = (_Float16)w0.y;
                f[2] = (_Float16)w0.z; f[3] = (_Float16)w0.w;
                f[4] = (_Float16)w1.x; f[5] = (_Float16)w1.y;
                f[6] = (_Float16)w1.z; f[7] = (_Float16)w1.w;
                bf[jt][kh] = f;
            }
        }
        const int wid = ((blk - HB) * PT + t) >> 6;
        const int nw  = (YGB * PT) >> 6;       // 4096 waves
        for (int nt = wid; nt < NN / 16; nt += nw) {   // 6250 tiles exact
            const int n0 = nt * 16;
            f16x8 af[2];
            #pragma unroll
            for (int kh = 0; kh < 2; ++kh) {
                const float* xp = x + (size_t)(n0 + m) * 64 + kh * 32 + kb * 8;
                const float4 x0 = *reinterpret_cast<const float4*>(xp);
                const float4 x1 = *reinterpret_cast<const float4*>(xp + 4);
                f16x8 f;
                f[0] = (_Float16)x0.x; f[1] = (_Float16)x0.y;
                f[2] = (_Float16)x0.z; f[3] = (_Float16)x0.w;
                f[4] = (_Float16)x1.x; f[5] = (_Float16)x1.y;
                f[6] = (_Float16)x1.z; f[7] = (_Float16)x1.w;
                af[kh] = f;
            }
            #pragma unroll
            for (int jt = 0; jt < 4; ++jt) {
                f32x4 acc = {0.f, 0.f, 0.f, 0.f};
                acc = __builtin_amdgcn_mfma_f32_16x16x32_f16(bf[jt][0], af[0], acc, 0, 0, 0);
                acc = __builtin_amdgcn_mfma_f32_16x16x32_f16(bf[jt][1], af[1], acc, 0, 0, 0);
                const size_t elem = (size_t)(n0 + m) * 64 + jt * 16 + kb * 4;
                union { uint2 u; __half h[4]; } pk;
                pk.h[0] = __float2half(acc[0]); pk.h[1] = __float2half(acc[1]);
                pk.h[2] = __float2half(acc[2]); pk.h[3] = __float2half(acc[3]);
                *reinterpret_cast<uint2*>(y + elem) = pk.u;
            }
        }
    }
}

// ---- per-scan-block sums ----
__global__ void scanpart_kernel(const int* __restrict__ a, int* __restrict__ bsum) {
    __shared__ int red[16];
    const int t = threadIdx.x;
    const int i = blockIdx.x * SCB + t;
    int s = (i < NST) ? a[i] : 0;
    #pragma unroll
    for (int o = 1; o < 64; o <<= 1) s += __shfl_xor(s, o);
    if ((t & 63) == 0) red[t >> 6] = s;
    __syncthreads();
    if (t < 16) {
        int ss = red[t];
        #pragma unroll
        for (int o = 1; o < 16; o <<= 1) ss += __shfl_xor(ss, o);
        if (t == 0) bsum[blockIdx.x] = ss;
    }
}

// in-place final scan; block prefix computed here from bsum (no scanblk kernel)
__global__ void scanfinal_kernel(int* __restrict__ a, const int* __restrict__ bsum) {
    __shared__ int wsum[16], wsum2[16], red[16];
    __shared__ int prefix_s;
    const int t = threadIdx.x;
    const int i = blockIdx.x * SCB + t;
    const int lane = t & 63;
    const int w = t >> 6;
    // prefix over bsum[0 .. blockIdx.x)
    int pv = (t < blockIdx.x) ? bsum[t] : 0;   // blockIdx < SCG=478 < 1024
    #pragma unroll
    for (int o = 1; o < 64; o <<= 1) pv += __shfl_xor(pv, o);
    if (lane == 0) red[w] = pv;
    // per-element wave scan
    const int v = (i < NST) ? a[i] : 0;
    int s = v;
    #pragma unroll
    for (int o = 1; o < 64; o <<= 1) { int u = __shfl_up(s, o); if (lane >= o) s += u; }
    if (lane == 63) wsum[w] = s;
    __syncthreads();
    if (t < 16) {
        int ss = wsum[t];
        #pragma unroll
        for (int o = 1; o < 16; o <<= 1) { int u = __shfl_up(ss, o); if (t >= o) ss += u; }
        wsum2[t] = ss;
        int rr = red[t];
        #pragma unroll
        for (int o = 1; o < 16; o <<= 1) rr += __shfl_xor(rr, o);
        if (t == 0) prefix_s = rr;
    }
    __syncthreads();
    const int excl = prefix_s + (w ? wsum2[w - 1] : 0) + (s - v);
    if (i < NST) a[i] = excl;
}

// ---- fused scatter: row payload u32 + col digit byte, one vectorized pass ----
__global__ void __launch_bounds__(HT)
scatboth_kernel(const int* __restrict__ row, const int* __restrict__ col,
                const float* __restrict__ dist, const int* __restrict__ hoff,
                unsigned* __restrict__ payload, unsigned char* __restrict__ colidx) {
    __shared__ int cur_r[NRB];
    __shared__ int cur_c[NCB];
    const int t = threadIdx.x;
    for (int i = t; i < NRB; i += HT) cur_r[i] = hoff[i * HB + blockIdx.x];
    for (int i = t; i < NCB; i += HT) cur_c[i] = hoff[NSR + i * HB + blockIdx.x] - NE;
    __syncthreads();
    const int e0 = blockIdx.x * CHUNK;
    for (int e = e0 + t * 4; e < e0 + CHUNK; e += HT * 4) {
        const int4 r4 = *reinterpret_cast<const int4*>(row + e);
        const int4 c4 = *reinterpret_cast<const int4*>(col + e);
        const float4 d4 = *reinterpret_cast<const float4*>(dist + e);
        const int rr[4] = {r4.x, r4.y, r4.z, r4.w};
        const int cc[4] = {c4.x, c4.y, c4.z, c4.w};
        const float dd[4] = {d4.x, d4.y, d4.z, d4.w};
        #pragma unroll
        for (int j = 0; j < 4; ++j) {
            const int r = rr[j];
            const int c = cc[j];
            const float dv = dd[j];
            const unsigned w8 = (unsigned)(__expf(-dv * dv) * 255.0f + 0.5f);
            const int pr = atomicAdd(&cur_r[r >> 6], 1);
            payload[pr] = ((unsigned)(r & 63) << 25) | (w8 << 17) | (unsigned)c;
            const int pc = atomicAdd(&cur_c[c >> 8], 1);
            colidx[pc] = (unsigned char)(c & 255);
        }
    }
}

// ---- per-col-bucket exact degree count -> dinv (256 nodes/bucket) ----
__global__ void __launch_bounds__(256)
coldinv_kernel(const int* __restrict__ hoff, const unsigned char* __restrict__ colidx,
               float* __restrict__ dinv) {
    __shared__ int cnt[256];
    const int t = threadIdx.x;
    const int b = blockIdx.x;
    cnt[t] = 0;
    __syncthreads();
    const int s0 = hoff[NSR + b * HB] - NE;
    const int s1 = (b + 1 < NCB) ? (hoff[NSR + (b + 1) * HB] - NE) : NE;
    for (int k = s0 + t; k < s1; k += 256) atomicAdd(&cnt[colidx[k]], 1);
    __syncthreads();
    const int n = b * 256 + t;
    if (n < NN) {
        const int d = cnt[t];
        dinv[n] = (d > 0) ? rsqrtf((float)d) : 0.0f;
    }
}

// ---- fused counting-sort + gather + epilogue, one block per 64-node bucket.
// 512 threads = 8 waves; each wave gathers 8 nodes, 8 edges in flight. ----
__global__ void __launch_bounds__(GT)
gather_fused_kernel(const int* __restrict__ hoff, const unsigned* __restrict__ payload,
                    const float* __restrict__ dinvg, const __half* __restrict__ y,
                    const float* __restrict__ bias, float* __restrict__ out) {
    __shared__ unsigned stage[CAP];    // 6KB
    __shared__ unsigned sorted[CAP];   // 6KB
    __shared__ int cnt[64], cur[64], rs[65];
    __shared__ float dinv_s[64];
    const int t = threadIdx.x;
    const int lane = t & 63;
    const int wv = t >> 6;            // 0..7
    const int b = blockIdx.x;
    const int sub = lane >> 3;        // which of 8 concurrent edges
    const int ch8 = (lane & 7) << 3;  // 8 channels per lane
    constexpr float WSCL = 1.0f / 255.0f;
    const float4 b0 = *reinterpret_cast<const float4*>(bias + ch8);
    const float4 b1 = *reinterpret_cast<const float4*>(bias + ch8 + 4);

    if (t < 64) {
        cnt[t] = 0;
        const int n = b * 64 + t;
        dinv_s[t] = (n < NN) ? dinvg[n] : 0.0f;
    }
    const int s0g = hoff[b * HB];
    const int s1g = (b + 1 < NRB) ? hoff[(b + 1) * HB] : NE;
    int ne = s1g - s0g;
    ne = (ne < CAP) ? ne : CAP;       // impossible-overflow guard
    __syncthreads();
    for (int k = t; k < ne; k += GT) {
        const unsigned p = payload[s0g + k];
        stage[k] = p;
        atomicAdd(&cnt[p >> 25], 1);
    }
    __syncthreads();
    if (t < 64) {                     // wave 0 scans the 64 counts
        const int v = cnt[t];
        int s = v;
        #pragma unroll
        for (int o = 1; o < 64; o <<= 1) { int u = __shfl_up(s, o); if (t >= o) s += u; }
        cur[t] = s - v;
        rs[t] = s - v;
        if (t == 63) rs[64] = s;
    }
    __syncthreads();
    for (int k = t; k < ne; k += GT) {
        const unsigned p = stage[k];
        const int pos = atomicAdd(&cur[p >> 25], 1);
        sorted[pos] = p;
    }
    __syncthreads();

    for (int ln = wv; ln < 64; ln += 8) {    // 8 nodes per wave
        const int n = b * 64 + ln;
        if (n >= NN) break;                  // wave-uniform (last bucket only)
        const int e0 = rs[ln];
        const int e1 = rs[ln + 1];
        float a0 = 0.f, a1 = 0.f, a2 = 0.f, a3 = 0.f;
        float a4 = 0.f, a5 = 0.f, a6 = 0.f, a7 = 0.f;
        for (int p0 = e0; p0 < e1; p0 += 8) {
            const int pp = p0 + sub;
            const int ppc = (pp < e1) ? pp : (e1 - 1);   // clamped -> valid read
            const unsigned m = sorted[ppc];
            const int c = (int)(m & 0x1FFFFu);
            float wgt = (float)((m >> 17) & 255u) * WSCL * dinvg[c];
            wgt = (pp < e1) ? wgt : 0.0f;
            const float4 raw = *reinterpret_cast<const float4*>(y + (size_t)c * 64 + ch8);
            const __half2* h2 = reinterpret_cast<const __half2*>(&raw);
            const float2 f0 = __half22float2(h2[0]);
            const float2 f1 = __half22float2(h2[1]);
            const float2 f2 = __half22float2(h2[2]);
            const float2 f3 = __half22float2(h2[3]);
            a0 += wgt * f0.x; a1 += wgt * f0.y; a2 += wgt * f1.x; a3 += wgt * f1.y;
            a4 += wgt * f2.x; a5 += wgt * f2.y; a6 += wgt * f3.x; a7 += wgt * f3.y;
        }
        #pragma unroll
        for (int o = 8; o < 64; o <<= 1) {
            a0 += __shfl_xor(a0, o); a1 += __shfl_xor(a1, o);
            a2 += __shfl_xor(a2, o); a3 += __shfl_xor(a3, o);
            a4 += __shfl_xor(a4, o); a5 += __shfl_xor(a5, o);
            a6 += __shfl_xor(a6, o); a7 += __shfl_xor(a7, o);
        }
        if (sub == 0) {
            const float dn = dinv_s[ln];
            const float4 o0 = make_float4(b0.x + dn * a0, b0.y + dn * a1,
                                          b0.z + dn * a2, b0.w + dn * a3);
            const float4 o1 = make_float4(b1.x + dn * a4, b1.y + dn * a5,
                                          b1.z + dn * a6, b1.w + dn * a7);
            float* op = out + (size_t)n * 64 + ch8;
            *reinterpret_cast<float4*>(op)     = o0;
            *reinterpret_cast<float4*>(op + 4) = o1;
        }
    }
}

extern "C" void kernel_launch(void* const* d_in, const int* in_sizes, int n_in,
                              void* d_out, int out_size, void* d_ws, size_t ws_size,
                              hipStream_t stream) {
    const float* x    = (const float*)d_in[0];
    const int*   ei   = (const int*)d_in[1];
    const float* dist = (const float*)d_in[2];
    const float* W    = (const float*)d_in[3];
    const float* b    = (const float*)d_in[4];
    float* out = (float*)d_out;

    const int* row = ei;
    const int* col = ei + NE;

    // workspace (~23.2 MB)
    unsigned*      payload = (unsigned*)d_ws;                   // NE u32 (6.4 MB)
    __half*        y       = (__half*)(payload + NE);           // NN*64 fp16 (12.8 MB)
    int*           hist    = (int*)(y + (size_t)NN * 64);       // NST (1.95 MB)
    int*           bsum    = hist + NST;                        // SCG
    unsigned char* colidx  = (unsigned char*)(bsum + SCG);      // NE bytes (1.6 MB)
    float*         dinv    = (float*)(colidx + NE);             // NN (0.4 MB)

    prep_kernel     <<<HB + YGB, PT, 0, stream>>>(x, W, y, row, col, hist);
    scanpart_kernel <<<SCG, SCB, 0, stream>>>(hist, bsum);
    scanfinal_kernel<<<SCG, SCB, 0, stream>>>(hist, bsum);
    scatboth_kernel <<<HB, HT, 0, stream>>>(row, col, dist, hist, payload, colidx);
    coldinv_kernel  <<<NCB, 256, 0, stream>>>(hist, colidx, dinv);
    gather_fused_kernel<<<NRB, GT, 0, stream>>>(hist, payload, dinv, y, b, out);
}

// Round 19
// 106.887 us; speedup vs baseline: 1.9217x; 1.0475x over previous
//
#include <hip/hip_runtime.h>
#include <hip/hip_fp16.h>

// Geo_GCN, zero-global-atomic pipeline + W pulled through the edge sum:
//   out[n] = b + dinv[n] * sum_e w_e * dinv[c_e] * y[c_e],  y = x @ W^T (MFMA, fp16)
// Edge record = ONE u32: digit(r&63)<<25 | w8<<17 | c(17b).
// Pipeline: prep (ygemm || hist2) -> scanpart -> scanfinal(+prefix) ->
//           scatboth (row-part || col-part, block-split) -> coldinv ->
//           gather_fused (512thr, 2 nodes/wave = 16 chains in flight).

constexpr int NN   = 100000;
constexpr int NE   = 1600000;
constexpr int D    = 64;
constexpr int NRB  = (NN + 63) / 64;          // 1563 row-buckets of 64 nodes
constexpr int NCB  = (NN + 255) / 256;        // 391 col-buckets of 256 nodes
constexpr int HB   = 250;                     // hist/scatter chunk grid
constexpr int HT   = 1024;                    // scatboth block size
constexpr int PT   = 512;                     // prep block size
constexpr int YGB  = 512;                     // ygemm blocks inside prep
constexpr int GT   = 512;                     // gather block size (8 waves)
constexpr int CHUNK = NE / HB;                // 6400 (exact, 16B-aligned chunks)
constexpr int NSR  = NRB * HB;                // 390750 row-hist elements
constexpr int NSCC = NCB * HB;                // 97750 col-hist elements
constexpr int NST  = NSR + NSCC;              // 488500 combined scan
constexpr int SCB  = 1024;
constexpr int SCG  = (NST + SCB - 1) / SCB;   // 478 scan blocks
constexpr int CAP  = 1536;                    // bucket edge cap (mean 1024, +16 sigma)

using f16x8 = __attribute__((ext_vector_type(8))) _Float16;
using f32x4 = __attribute__((ext_vector_type(4))) float;

// ---- pass 1: FUSED ygemm (MFMA) || hist2 (LDS histograms), block-partitioned.
__global__ void __launch_bounds__(PT)
prep_kernel(const float* __restrict__ x, const float* __restrict__ W,
            __half* __restrict__ y, const int* __restrict__ row,
            const int* __restrict__ col, int* __restrict__ hist) {
    __shared__ int hr[NRB], hc[NCB];
    const int t = threadIdx.x;
    const int blk = blockIdx.x;
    if (blk < HB) {
        // ---------------- hist2 part ----------------
        for (int i = t; i < NRB; i += PT) hr[i] = 0;
        for (int i = t; i < NCB; i += PT) hc[i] = 0;
        __syncthreads();
        const int e0 = blk * CHUNK;
        for (int e = e0 + t * 4; e < e0 + CHUNK; e += PT * 4) {
            const int4 r4 = *reinterpret_cast<const int4*>(row + e);
            const int4 c4 = *reinterpret_cast<const int4*>(col + e);
            atomicAdd(&hr[r4.x >> 6], 1); atomicAdd(&hr[r4.y >> 6], 1);
            atomicAdd(&hr[r4.z >> 6], 1); atomicAdd(&hr[r4.w >> 6], 1);
            atomicAdd(&hc[c4.x >> 8], 1); atomicAdd(&hc[c4.y >> 8], 1);
            atomicAdd(&hc[c4.z >> 8], 1); atomicAdd(&hc[c4.w >> 8], 1);
        }
        __syncthreads();
        for (int i = t; i < NRB; i += PT) hist[i * HB + blk] = hr[i];
        for (int i = t; i < NCB; i += PT) hist[NSR + i * HB + blk] = hc[i];
    } else {
        // ---------------- ygemm part ----------------
        const int m  = t & 15;
        const int kb = (t & 63) >> 4;
        f16x8 bf[4][2];
        #pragma unroll
        for (int jt = 0; jt < 4; ++jt) {
            #pragma unroll
            for (int kh = 0; kh < 2; ++kh) {
                const float* wp = W + (size_t)(jt * 16 + m) * 64 + kh * 32 + kb * 8;
                const float4 w0 = *reinterpret_cast<const float4*>(wp);
                const float4 w1 = *reinterpret_cast<const float4*>(wp + 4);
                f16x8 f;
                f[0] = (_Float16)w0.x; f[1] = (_Float16)w0.y;
                f[2] = (_Float16)w0.z; f[3] = (_Float16)w0.w;
                f[4] = (_Float16)w1.x; f[5] = (_Float16)w1.y;
                f[6] = (_Float16)w1.z; f[7] = (_Float16)w1.w;
                bf[jt][kh] = f;
            }
        }
        const int wid = ((blk - HB) * PT + t) >> 6;
        const int nw  = (YGB * PT) >> 6;       // 4096 waves
        for (int nt = wid; nt < NN / 16; nt += nw) {   // 6250 tiles exact
            const int n0 = nt * 16;
            f16x8 af[2];
            #pragma unroll
            for (int kh = 0; kh < 2; ++kh) {
                const float* xp = x + (size_t)(n0 + m) * 64 + kh * 32 + kb * 8;
                const float4 x0 = *reinterpret_cast<const float4*>(xp);
                const float4 x1 = *reinterpret_cast<const float4*>(xp + 4);
                f16x8 f;
                f[0] = (_Float16)x0.x; f[1] = (_Float16)x0.y;
                f[2] = (_Float16)x0.z; f[3] = (_Float16)x0.w;
                f[4] = (_Float16)x1.x; f[5] = (_Float16)x1.y;
                f[6] = (_Float16)x1.z; f[7] = (_Float16)x1.w;
                af[kh] = f;
            }
            #pragma unroll
            for (int jt = 0; jt < 4; ++jt) {
                f32x4 acc = {0.f, 0.f, 0.f, 0.f};
                acc = __builtin_amdgcn_mfma_f32_16x16x32_f16(bf[jt][0], af[0], acc, 0, 0, 0);
                acc = __builtin_amdgcn_mfma_f32_16x16x32_f16(bf[jt][1], af[1], acc, 0, 0, 0);
                const size_t elem = (size_t)(n0 + m) * 64 + jt * 16 + kb * 4;
                union { uint2 u; __half h[4]; } pk;
                pk.h[0] = __float2half(acc[0]); pk.h[1] = __float2half(acc[1]);
                pk.h[2] = __float2half(acc[2]); pk.h[3] = __float2half(acc[3]);
                *reinterpret_cast<uint2*>(y + elem) = pk.u;
            }
        }
    }
}

// ---- per-scan-block sums ----
__global__ void scanpart_kernel(const int* __restrict__ a, int* __restrict__ bsum) {
    __shared__ int red[16];
    const int t = threadIdx.x;
    const int i = blockIdx.x * SCB + t;
    int s = (i < NST) ? a[i] : 0;
    #pragma unroll
    for (int o = 1; o < 64; o <<= 1) s += __shfl_xor(s, o);
    if ((t & 63) == 0) red[t >> 6] = s;
    __syncthreads();
    if (t < 16) {
        int ss = red[t];
        #pragma unroll
        for (int o = 1; o < 16; o <<= 1) ss += __shfl_xor(ss, o);
        if (t == 0) bsum[blockIdx.x] = ss;
    }
}

// in-place final scan; block prefix computed here from bsum (no scanblk kernel)
__global__ void scanfinal_kernel(int* __restrict__ a, const int* __restrict__ bsum) {
    __shared__ int wsum[16], wsum2[16], red[16];
    __shared__ int prefix_s;
    const int t = threadIdx.x;
    const int i = blockIdx.x * SCB + t;
    const int lane = t & 63;
    const int w = t >> 6;
    // prefix over bsum[0 .. blockIdx.x)
    int pv = (t < blockIdx.x) ? bsum[t] : 0;   // blockIdx < SCG=478 < 1024
    #pragma unroll
    for (int o = 1; o < 64; o <<= 1) pv += __shfl_xor(pv, o);
    if (lane == 0) red[w] = pv;
    // per-element wave scan
    const int v = (i < NST) ? a[i] : 0;
    int s = v;
    #pragma unroll
    for (int o = 1; o < 64; o <<= 1) { int u = __shfl_up(s, o); if (lane >= o) s += u; }
    if (lane == 63) wsum[w] = s;
    __syncthreads();
    if (t < 16) {
        int ss = wsum[t];
        #pragma unroll
        for (int o = 1; o < 16; o <<= 1) { int u = __shfl_up(ss, o); if (t >= o) ss += u; }
        wsum2[t] = ss;
        int rr = red[t];
        #pragma unroll
        for (int o = 1; o < 16; o <<= 1) rr += __shfl_xor(rr, o);
        if (t == 0) prefix_s = rr;
    }
    __syncthreads();
    const int excl = prefix_s + (w ? wsum2[w - 1] : 0) + (s - v);
    if (i < NST) a[i] = excl;
}

// ---- block-split scatter: blocks [0,HB) place row payloads; blocks
// [HB,2*HB) place col digit bytes. Doubles CU coverage of the two
// random-store streams. ----
__global__ void __launch_bounds__(HT)
scatboth_kernel(const int* __restrict__ row, const int* __restrict__ col,
                const float* __restrict__ dist, const int* __restrict__ hoff,
                unsigned* __restrict__ payload, unsigned char* __restrict__ colidx) {
    __shared__ int cur[NRB];          // row part uses [0,NRB); col part [0,NCB)
    const int t = threadIdx.x;
    const bool rowpart = blockIdx.x < HB;
    const int blk = rowpart ? blockIdx.x : (blockIdx.x - HB);
    const int e0 = blk * CHUNK;
    if (rowpart) {
        for (int i = t; i < NRB; i += HT) cur[i] = hoff[i * HB + blk];
        __syncthreads();
        for (int e = e0 + t * 4; e < e0 + CHUNK; e += HT * 4) {
            const int4 r4 = *reinterpret_cast<const int4*>(row + e);
            const int4 c4 = *reinterpret_cast<const int4*>(col + e);
            const float4 d4 = *reinterpret_cast<const float4*>(dist + e);
            const int rr[4] = {r4.x, r4.y, r4.z, r4.w};
            const int cc[4] = {c4.x, c4.y, c4.z, c4.w};
            const float dd[4] = {d4.x, d4.y, d4.z, d4.w};
            #pragma unroll
            for (int j = 0; j < 4; ++j) {
                const int r = rr[j];
                const float dv = dd[j];
                const unsigned w8 = (unsigned)(__expf(-dv * dv) * 255.0f + 0.5f);
                const int pr = atomicAdd(&cur[r >> 6], 1);
                payload[pr] = ((unsigned)(r & 63) << 25) | (w8 << 17) | (unsigned)cc[j];
            }
        }
    } else {
        for (int i = t; i < NCB; i += HT) cur[i] = hoff[NSR + i * HB + blk] - NE;
        __syncthreads();
        for (int e = e0 + t * 4; e < e0 + CHUNK; e += HT * 4) {
            const int4 c4 = *reinterpret_cast<const int4*>(col + e);
            const int cc[4] = {c4.x, c4.y, c4.z, c4.w};
            #pragma unroll
            for (int j = 0; j < 4; ++j) {
                const int c = cc[j];
                const int pc = atomicAdd(&cur[c >> 8], 1);
                colidx[pc] = (unsigned char)(c & 255);
            }
        }
    }
}

// ---- per-col-bucket exact degree count -> dinv (256 nodes/bucket) ----
__global__ void __launch_bounds__(256)
coldinv_kernel(const int* __restrict__ hoff, const unsigned char* __restrict__ colidx,
               float* __restrict__ dinv) {
    __shared__ int cnt[256];
    const int t = threadIdx.x;
    const int b = blockIdx.x;
    cnt[t] = 0;
    __syncthreads();
    const int s0 = hoff[NSR + b * HB] - NE;
    const int s1 = (b + 1 < NCB) ? (hoff[NSR + (b + 1) * HB] - NE) : NE;
    for (int k = s0 + t; k < s1; k += 256) atomicAdd(&cnt[colidx[k]], 1);
    __syncthreads();
    const int n = b * 256 + t;
    if (n < NN) {
        const int d = cnt[t];
        dinv[n] = (d > 0) ? rsqrtf((float)d) : 0.0f;
    }
}

// ---- fused counting-sort + gather + epilogue, one block per 64-node bucket.
// 512 threads = 8 waves; each wave handles 2 NODES CONCURRENTLY (16 y-load
// chains in flight) over 4 pair-iterations. ----
__global__ void __launch_bounds__(GT)
gather_fused_kernel(const int* __restrict__ hoff, const unsigned* __restrict__ payload,
                    const float* __restrict__ dinvg, const __half* __restrict__ y,
                    const float* __restrict__ bias, float* __restrict__ out) {
    __shared__ unsigned stage[CAP];    // 6KB
    __shared__ unsigned sorted[CAP];   // 6KB
    __shared__ int cnt[64], cur[64], rs[65];
    __shared__ float dinv_s[64];
    const int t = threadIdx.x;
    const int lane = t & 63;
    const int wv = t >> 6;            // 0..7
    const int b = blockIdx.x;
    const int sub = lane >> 3;        // which of 8 concurrent edges per node
    const int ch8 = (lane & 7) << 3;  // 8 channels per lane
    constexpr float WSCL = 1.0f / 255.0f;
    const float4 b0 = *reinterpret_cast<const float4*>(bias + ch8);
    const float4 b1 = *reinterpret_cast<const float4*>(bias + ch8 + 4);

    if (t < 64) {
        cnt[t] = 0;
        const int n = b * 64 + t;
        dinv_s[t] = (n < NN) ? dinvg[n] : 0.0f;
    }
    const int s0g = hoff[b * HB];
    const int s1g = (b + 1 < NRB) ? hoff[(b + 1) * HB] : NE;
    int ne = s1g - s0g;
    ne = (ne < CAP) ? ne : CAP;       // impossible-overflow guard
    __syncthreads();
    for (int k = t; k < ne; k += GT) {
        const unsigned p = payload[s0g + k];
        stage[k] = p;
        atomicAdd(&cnt[p >> 25], 1);
    }
    __syncthreads();
    if (t < 64) {                     // wave 0 scans the 64 counts
        const int v = cnt[t];
        int s = v;
        #pragma unroll
        for (int o = 1; o < 64; o <<= 1) { int u = __shfl_up(s, o); if (t >= o) s += u; }
        cur[t] = s - v;
        rs[t] = s - v;
        if (t == 63) rs[64] = s;
    }
    __syncthreads();
    for (int k = t; k < ne; k += GT) {
        const unsigned p = stage[k];
        const int pos = atomicAdd(&cur[p >> 25], 1);
        sorted[pos] = p;
    }
    __syncthreads();

    const int ne1 = (ne > 0) ? (ne - 1) : 0;
    #pragma unroll
    for (int pr = 0; pr < 4; ++pr) {          // 2 nodes per wave per iteration
        const int lnA = wv + pr * 16;         // 0..55 + wv
        const int lnB = lnA + 8;              // 8..63 + wv
        const int e0A = rs[lnA], e1A = rs[lnA + 1];
        const int e0B = rs[lnB], e1B = rs[lnB + 1];
        const int itA = (e1A - e0A + 7) >> 3;
        const int itB = (e1B - e0B + 7) >> 3;
        const int iters = (itA > itB) ? itA : itB;
        float a0 = 0.f, a1 = 0.f, a2 = 0.f, a3 = 0.f;
        float a4 = 0.f, a5 = 0.f, a6 = 0.f, a7 = 0.f;
        float c0 = 0.f, c1 = 0.f, c2 = 0.f, c3 = 0.f;
        float c4 = 0.f, c5 = 0.f, c6 = 0.f, c7 = 0.f;
        for (int i = 0; i < iters; ++i) {
            const int ppA = e0A + i * 8 + sub;
            const int ppB = e0B + i * 8 + sub;
            const bool okA = ppA < e1A;
            const bool okB = ppB < e1B;
            const unsigned mA = sorted[okA ? ppA : ne1];
            const unsigned mB = sorted[okB ? ppB : ne1];
            const int cA = (int)(mA & 0x1FFFFu);
            const int cB = (int)(mB & 0x1FFFFu);
            float wA = (float)((mA >> 17) & 255u) * WSCL * dinvg[cA];
            float wB = (float)((mB >> 17) & 255u) * WSCL * dinvg[cB];
            wA = okA ? wA : 0.0f;
            wB = okB ? wB : 0.0f;
            const float4 rawA = *reinterpret_cast<const float4*>(y + (size_t)cA * 64 + ch8);
            const float4 rawB = *reinterpret_cast<const float4*>(y + (size_t)cB * 64 + ch8);
            const __half2* hA = reinterpret_cast<const __half2*>(&rawA);
            const __half2* hB = reinterpret_cast<const __half2*>(&rawB);
            const float2 fA0 = __half22float2(hA[0]);
            const float2 fA1 = __half22float2(hA[1]);
            const float2 fA2 = __half22float2(hA[2]);
            const float2 fA3 = __half22float2(hA[3]);
            a0 += wA * fA0.x; a1 += wA * fA0.y; a2 += wA * fA1.x; a3 += wA * fA1.y;
            a4 += wA * fA2.x; a5 += wA * fA2.y; a6 += wA * fA3.x; a7 += wA * fA3.y;
            const float2 fB0 = __half22float2(hB[0]);
            const float2 fB1 = __half22float2(hB[1]);
            const float2 fB2 = __half22float2(hB[2]);
            const float2 fB3 = __half22float2(hB[3]);
            c0 += wB * fB0.x; c1 += wB * fB0.y; c2 += wB * fB1.x; c3 += wB * fB1.y;
            c4 += wB * fB2.x; c5 += wB * fB2.y; c6 += wB * fB3.x; c7 += wB * fB3.y;
        }
        #pragma unroll
        for (int o = 8; o < 64; o <<= 1) {
            a0 += __shfl_xor(a0, o); a1 += __shfl_xor(a1, o);
            a2 += __shfl_xor(a2, o); a3 += __shfl_xor(a3, o);
            a4 += __shfl_xor(a4, o); a5 += __shfl_xor(a5, o);
            a6 += __shfl_xor(a6, o); a7 += __shfl_xor(a7, o);
            c0 += __shfl_xor(c0, o); c1 += __shfl_xor(c1, o);
            c2 += __shfl_xor(c2, o); c3 += __shfl_xor(c3, o);
            c4 += __shfl_xor(c4, o); c5 += __shfl_xor(c5, o);
            c6 += __shfl_xor(c6, o); c7 += __shfl_xor(c7, o);
        }
        const int nA = b * 64 + lnA;
        const int nB = b * 64 + lnB;
        if (sub == 0 && nA < NN) {
            const float dn = dinv_s[lnA];
            const float4 o0 = make_float4(b0.x + dn * a0, b0.y + dn * a1,
                                          b0.z + dn * a2, b0.w + dn * a3);
            const float4 o1 = make_float4(b1.x + dn * a4, b1.y + dn * a5,
                                          b1.z + dn * a6, b1.w + dn * a7);
            float* op = out + (size_t)nA * 64 + ch8;
            *reinterpret_cast<float4*>(op)     = o0;
            *reinterpret_cast<float4*>(op + 4) = o1;
        } else if (sub == 1 && nB < NN) {
            const float dn = dinv_s[lnB];
            const float4 o0 = make_float4(b0.x + dn * c0, b0.y + dn * c1,
                                          b0.z + dn * c2, b0.w + dn * c3);
            const float4 o1 = make_float4(b1.x + dn * c4, b1.y + dn * c5,
                                          b1.z + dn * c6, b1.w + dn * c7);
            float* op = out + (size_t)nB * 64 + ch8;
            *reinterpret_cast<float4*>(op)     = o0;
            *reinterpret_cast<float4*>(op + 4) = o1;
        }
    }
}

extern "C" void kernel_launch(void* const* d_in, const int* in_sizes, int n_in,
                              void* d_out, int out_size, void* d_ws, size_t ws_size,
                              hipStream_t stream) {
    const float* x    = (const float*)d_in[0];
    const int*   ei   = (const int*)d_in[1];
    const float* dist = (const float*)d_in[2];
    const float* W    = (const float*)d_in[3];
    const float* b    = (const float*)d_in[4];
    float* out = (float*)d_out;

    const int* row = ei;
    const int* col = ei + NE;

    // workspace (~23.2 MB)
    unsigned*      payload = (unsigned*)d_ws;                   // NE u32 (6.4 MB)
    __half*        y       = (__half*)(payload + NE);           // NN*64 fp16 (12.8 MB)
    int*           hist    = (int*)(y + (size_t)NN * 64);       // NST (1.95 MB)
    int*           bsum    = hist + NST;                        // SCG
    unsigned char* colidx  = (unsigned char*)(bsum + SCG);      // NE bytes (1.6 MB)
    float*         dinv    = (float*)(colidx + NE);             // NN (0.4 MB)

    prep_kernel     <<<HB + YGB, PT, 0, stream>>>(x, W, y, row, col, hist);
    scanpart_kernel <<<SCG, SCB, 0, stream>>>(hist, bsum);
    scanfinal_kernel<<<SCG, SCB, 0, stream>>>(hist, bsum);
    scatboth_kernel <<<HB * 2, HT, 0, stream>>>(row, col, dist, hist, payload, colidx);
    coldinv_kernel  <<<NCB, 256, 0, stream>>>(hist, colidx, dinv);
    gather_fused_kernel<<<NRB, GT, 0, stream>>>(hist, payload, dinv, y, b, out);
}